// Round 9
// baseline (1351.726 us; speedup 1.0000x reference)
//
#include <hip/hip_runtime.h>
#include <hip/hip_bf16.h>

#define HD 768
#define N_NODES 16383
#define NLEAF_OFF 8191     // first leaf node index (level d=13 offset)
#define NHF 12582144       // N_NODES * HD
#define TEMP 3.0f

using bf16 = __hip_bfloat16;
typedef __attribute__((ext_vector_type(8))) short bf16x8;
typedef __attribute__((ext_vector_type(4))) float f32x4;

__device__ __forceinline__ float sigm(float x) { return 1.0f / (1.0f + __expf(-x)); }
__device__ __forceinline__ float b2f(bf16 v)   { return __bfloat162float(v); }
__device__ __forceinline__ bf16  f2b(float v)  { return __float2bfloat16(v); }
__device__ __forceinline__ short bs(float v)   { bf16 t = f2b(v); return *(short*)&t; }
__device__ __forceinline__ float sb(short v)   { bf16 t = *(bf16*)&v; return b2f(t); }

// async global->LDS, 16B per lane. LDS dest = wave-uniform base + lane*16.
__device__ __forceinline__ void gload16(const void* g, void* l) {
    __builtin_amdgcn_global_load_lds(
        (const __attribute__((address_space(1))) unsigned int*)g,
        (__attribute__((address_space(3))) unsigned int*)l, 16, 0, 0);
}

// ---------------------------------------------------------------------------
// ONE fused weight-conversion kernel (bf16 B^T, gate-major layouts).
// ---------------------------------------------------------------------------
#define T1SZ 5898240      // 3840*1536
#define T2SZ 10616832     // 4608*2304
#define WSZ  589824       // 768*768
#define HSZ  98304        // 128*768
#define CONVTOT (T1SZ + T2SZ + 2*WSZ + HSZ)

__global__ __launch_bounds__(256) void conv_k(
    const float* __restrict__ Ub_iou, const float* __restrict__ Ub_f,
    const float* __restrict__ Ut_iou, const float* __restrict__ Ut_f,
    const float* __restrict__ ffn_W1, const float* __restrict__ ffn_W2,
    const float* __restrict__ hlW, const float* __restrict__ intW,
    const float* __restrict__ actW,
    bf16* __restrict__ BT1, bf16* __restrict__ BT2,
    bf16* __restrict__ W1T, bf16* __restrict__ W2T, bf16* __restrict__ WhT)
{
    int idx = blockIdx.x * 256 + threadIdx.x;
    if (idx >= CONVTOT) return;
    if (idx < T1SZ) {
        int n = idx / 1536, k = idx - n * 1536;
        int l = (k >= 768);
        int h = k - l * 768;
        float v;
        if (n < 2304) v = Ub_iou[(size_t)k * 2304 + n];
        else {
            int c2 = n - 2304;
            int kk = c2 / 768, o = c2 - kk * 768;
            v = Ub_f[(((size_t)(kk * 2 + l)) * 768 + h) * 768 + o];
        }
        BT1[idx] = f2b(v);
    } else if (idx < T1SZ + T2SZ) {
        int i2 = idx - T1SZ;
        int n = i2 / 2304, k = i2 - n * 2304;
        int l = (k >= 768) + (k >= 1536);
        int h = k - l * 768;
        float v;
        if (n < 2304) v = Ut_iou[(size_t)k * 2304 + n];
        else {
            int c2 = n - 2304;
            int kk = c2 / 768, o = c2 - kk * 768;
            v = Ut_f[(((size_t)(kk * 3 + l)) * 768 + h) * 768 + o];
        }
        BT2[i2] = f2b(v);
    } else if (idx < T1SZ + T2SZ + WSZ) {
        int i2 = idx - T1SZ - T2SZ;
        int n = i2 / 768, k = i2 - n * 768;
        W1T[i2] = f2b(ffn_W1[(size_t)k * 768 + n]);
    } else if (idx < T1SZ + T2SZ + 2 * WSZ) {
        int i2 = idx - T1SZ - T2SZ - WSZ;
        int n = i2 / 768, k = i2 - n * 768;
        W2T[i2] = f2b(ffn_W2[(size_t)k * 768 + n]);
    } else {
        int i2 = idx - T1SZ - T2SZ - 2 * WSZ;
        int n = i2 / 768, k = i2 - n * 768;
        float v = 0.f;
        if (n < 2)       v = hlW[(size_t)k * 2 + n];
        else if (n < 4)  v = intW[(size_t)k * 2 + (n - 2)];
        else if (n < 68) v = actW[(size_t)k * 64 + (n - 4)];
        WhT[i2] = f2b(v);
    }
}

// ---------------------------------------------------------------------------
// Fused leaf kernel, vectorized (8 j per thread): pass-1 h,c AND pass-2 h3.
// ---------------------------------------------------------------------------
__global__ __launch_bounds__(256) void leaf_k(
    const int* __restrict__ ids,
    const float* __restrict__ Wb, const float* __restrict__ bb,
    const float* __restrict__ Wt, const float* __restrict__ bt,
    bf16* __restrict__ h_all, bf16* __restrict__ c_all, bf16* __restrict__ h3_all)
{
    int idx = blockIdx.x * 256 + threadIdx.x;
    if (idx >= 8192 * 96) return;
    int i = idx / 96, j8 = (idx - i * 96) * 8;
    int g = NLEAF_OFF + i;
    int id = ids[g];
    const float* w  = Wb + (size_t)id * 2304 + j8;
    const float* w2 = Wt + (size_t)id * 2304 + j8;
    float wi[8], wo[8], wu[8], bi[8], bo[8], bu[8];
#pragma unroll
    for (int u = 0; u < 8; ++u) {
        wi[u] = w[u]; wo[u] = w[768 + u]; wu[u] = w[1536 + u];
        bi[u] = bb[j8 + u]; bo[u] = bb[768 + j8 + u]; bu[u] = bb[1536 + j8 + u];
    }
    bf16x8 hv, cv, h3v;
#pragma unroll
    for (int u = 0; u < 8; ++u) {
        float iv = sigm(wi[u] + bi[u]);
        float ov = sigm(wo[u] + bo[u]);
        float gv = tanhf(wu[u] + bu[u]);
        float c = iv * gv;
        hv[u] = bs(ov * tanhf(c));
        cv[u] = bs(c);
    }
#pragma unroll
    for (int u = 0; u < 8; ++u) {
        float iv = sigm(w2[u] + bt[j8 + u]);
        float ov = sigm(w2[768 + u] + bt[768 + j8 + u]);
        float gv = tanhf(w2[1536 + u] + bt[1536 + j8 + u]);
        float c = iv * gv;
        h3v[u] = bs(ov * tanhf(c));
    }
    *(bf16x8*)(h_all + (size_t)g * HD + j8) = hv;
    *(bf16x8*)(c_all + (size_t)g * HD + j8) = cv;
    *(bf16x8*)(h3_all + (size_t)g * HD + j8) = h3v;
}

// ---------------------------------------------------------------------------
// bf16 MFMA GEMM: C[M x N] = A @ BT^T. 128x128 tile, BK=64, 4 waves,
// linear LDS [128][64], global_load_lds staging, XCD-swizzled 1D grid.
// GATHER=1 (pass 2): A row r = [h(r), h(2r+1), h(2r+2)] via per-lane sources.
// EPI 0: fp32 Cf. EPI 1: bias+relu bf16. EPI 2: bias bf16. EPI 3: plain bf16.
// ---------------------------------------------------------------------------
template <int EPI, int GATHER>
__global__ __launch_bounds__(256) void mm_k(
    const bf16* __restrict__ A, const bf16* __restrict__ BT,
    float* __restrict__ Cf, bf16* __restrict__ Cb,
    const float* __restrict__ bias,
    int M, int N, int K, int gy)
{
    __shared__ short As[128 * 64];
    __shared__ short Bs[128 * 64];

    int tid  = threadIdx.x;
    int lane = tid & 63;
    int wave = tid >> 6;
    int wr = wave >> 1, wc = wave & 1;

    // XCD swizzle (contiguous bx-panels per XCD); identity if T % 8 != 0
    int T = gridDim.x;
    int L = blockIdx.x;
    int v = ((T & 7) == 0) ? ((L & 7) * (T >> 3) + (L >> 3)) : L;
    int bx = v / gy, by = v - bx * gy;

    f32x4 acc[4][4] = {};

    int sr8 = lane >> 3;             // 0..7
    int sc  = (lane & 7) * 8;        // 0..56
    int arow[4];
#pragma unroll
    for (int q = 0; q < 4; ++q) {
        int r = by * 128 + q * 32 + wave * 8 + sr8;
        arow[q] = (r > M - 1) ? (M - 1) : r;
    }

    int fr = lane & 15;
    int fk = (lane >> 4) << 3;

    for (int kt = 0; kt < K; kt += 64) {
        if constexpr (GATHER) {
            int ch = (kt >= 768) + (kt >= 1536);
            int col = kt - ch * 768 + sc;
#pragma unroll
            for (int q = 0; q < 4; ++q) {
                int node = (ch == 0) ? arow[q] : (2 * arow[q] + ch);
                gload16(A + (size_t)node * HD + col, As + (q * 32 + wave * 8) * 64);
            }
        } else {
#pragma unroll
            for (int q = 0; q < 4; ++q)
                gload16(A + (size_t)arow[q] * K + kt + sc, As + (q * 32 + wave * 8) * 64);
        }
#pragma unroll
        for (int q = 0; q < 4; ++q)
            gload16(BT + (size_t)(bx * 128 + q * 32 + wave * 8 + sr8) * K + kt + sc,
                    Bs + (q * 32 + wave * 8) * 64);
        __syncthreads();

#pragma unroll
        for (int ks = 0; ks < 2; ++ks) {
            bf16x8 a[4], b[4];
#pragma unroll
            for (int m = 0; m < 4; m++)
                a[m] = *(const bf16x8*)(As + (wr * 64 + m * 16 + fr) * 64 + ks * 32 + fk);
#pragma unroll
            for (int n = 0; n < 4; n++)
                b[n] = *(const bf16x8*)(Bs + (wc * 64 + n * 16 + fr) * 64 + ks * 32 + fk);
#pragma unroll
            for (int m = 0; m < 4; m++)
#pragma unroll
                for (int n = 0; n < 4; n++)
                    acc[m][n] = __builtin_amdgcn_mfma_f32_16x16x32_bf16(
                        a[m], b[n], acc[m][n], 0, 0, 0);
        }
        __syncthreads();
    }

    int rbase = by * 128 + wr * 64 + ((lane >> 4) << 2);
    int cbase = bx * 128 + wc * 64 + fr;
#pragma unroll
    for (int m = 0; m < 4; m++) {
#pragma unroll
        for (int r = 0; r < 4; r++) {
            int row = rbase + m * 16 + r;
            if (row >= M) continue;
#pragma unroll
            for (int n = 0; n < 4; n++) {
                int col = cbase + n * 16;
                float v2 = acc[m][n][r];
                if constexpr (EPI == 1) {
                    v2 = fmaxf(v2 + bias[col], 0.f);
                    Cb[(size_t)row * N + col] = f2b(v2);
                } else if constexpr (EPI == 2) {
                    v2 = v2 + bias[col];
                    Cb[(size_t)row * N + col] = f2b(v2);
                } else if constexpr (EPI == 3) {
                    Cb[(size_t)row * N + col] = f2b(v2);
                } else {
                    Cf[(size_t)row * N + col] = v2;
                }
            }
        }
    }
}

// ---------------------------------------------------------------------------
// FUSED small-level kernel (pass 1, n < 512). 64x64x5-gate tile, BK=64.
// ---------------------------------------------------------------------------
__global__ __launch_bounds__(256) void fmm_k(
    const int* __restrict__ ids,
    const bf16* __restrict__ Abase,
    const bf16* __restrict__ BT,
    const float* __restrict__ Wiou, const float* __restrict__ biou,
    const float* __restrict__ Wf, const float* __restrict__ bfv,
    const bf16* __restrict__ c_all,
    bf16* __restrict__ h_out, bf16* __restrict__ c_out,
    int M, int off)
{
    constexpr int K = 1536;
    __shared__ short As[64 * 64];
    __shared__ short Bs[5 * 64 * 64];

    int tid  = threadIdx.x;
    int lane = tid & 63;
    int wave = tid >> 6;
    int wr = wave >> 1, wc = wave & 1;
    int bx = blockIdx.x, by = blockIdx.y;

    f32x4 acc[5][2][2] = {};

    int sr8 = lane >> 3;
    int sc  = (lane & 7) * 8;
    int aRow[2];
#pragma unroll
    for (int q = 0; q < 2; ++q) {
        int r = by * 64 + q * 32 + wave * 8 + sr8;
        aRow[q] = (r > M - 1) ? (M - 1) : r;
    }

    int fr = lane & 15;
    int fk = (lane >> 4) << 3;

    for (int kt = 0; kt < K; kt += 64) {
#pragma unroll
        for (int q = 0; q < 2; ++q)
            gload16(Abase + (size_t)aRow[q] * 1536 + kt + sc, As + (q * 32 + wave * 8) * 64);
#pragma unroll
        for (int gb = 0; gb < 5; ++gb)
#pragma unroll
            for (int q = 0; q < 2; ++q)
                gload16(BT + (size_t)(gb * 768 + bx * 64 + q * 32 + wave * 8 + sr8) * K + kt + sc,
                        Bs + (gb * 64 + q * 32 + wave * 8) * 64);
        __syncthreads();

#pragma unroll
        for (int ks = 0; ks < 2; ++ks) {
            bf16x8 a[2];
#pragma unroll
            for (int m = 0; m < 2; ++m)
                a[m] = *(const bf16x8*)(As + (wr * 32 + m * 16 + fr) * 64 + ks * 32 + fk);
#pragma unroll
            for (int g = 0; g < 5; ++g) {
                bf16x8 b0 = *(const bf16x8*)(Bs + ((g * 64) + wc * 32 + fr) * 64 + ks * 32 + fk);
                bf16x8 b1 = *(const bf16x8*)(Bs + ((g * 64) + wc * 32 + 16 + fr) * 64 + ks * 32 + fk);
                acc[g][0][0] = __builtin_amdgcn_mfma_f32_16x16x32_bf16(a[0], b0, acc[g][0][0], 0, 0, 0);
                acc[g][0][1] = __builtin_amdgcn_mfma_f32_16x16x32_bf16(a[0], b1, acc[g][0][1], 0, 0, 0);
                acc[g][1][0] = __builtin_amdgcn_mfma_f32_16x16x32_bf16(a[1], b0, acc[g][1][0], 0, 0, 0);
                acc[g][1][1] = __builtin_amdgcn_mfma_f32_16x16x32_bf16(a[1], b1, acc[g][1][1], 0, 0, 0);
            }
        }
        __syncthreads();
    }

    int lr4 = (lane >> 4) << 2;
    int c0  = bx * 64 + wc * 32 + fr;
#pragma unroll
    for (int m = 0; m < 2; ++m) {
#pragma unroll
        for (int r = 0; r < 4; ++r) {
            int row = by * 64 + wr * 32 + m * 16 + lr4 + r;
            if (row >= M) continue;
            int g = off + row;
            int id = ids[g];
            const float* wi = Wiou + (size_t)id * 2304;
            const float* wf = Wf + (size_t)id * 768;
#pragma unroll
            for (int n = 0; n < 2; ++n) {
                int j = c0 + n * 16;
                float iv = sigm(acc[0][m][n][r] + wi[j] + biou[j]);
                float ov = sigm(acc[1][m][n][r] + wi[768 + j] + biou[768 + j]);
                float uv = tanhf(acc[2][m][n][r] + wi[1536 + j] + biou[1536 + j]);
                float xf = wf[j] + bfv[j];
                float f0 = sigm(acc[3][m][n][r] + xf);
                float f1 = sigm(acc[4][m][n][r] + xf);
                float cv2 = iv * uv
                          + f0 * b2f(c_all[(size_t)(2 * g + 1) * HD + j])
                          + f1 * b2f(c_all[(size_t)(2 * g + 2) * HD + j]);
                c_out[(size_t)g * HD + j] = f2b(cv2);
                h_out[(size_t)g * HD + j] = f2b(ov * tanhf(cv2));
            }
        }
    }
}

// ---------------------------------------------------------------------------
// Pass-1 cell, vectorized (8 j per thread): bf16 S(m x 3840) -> h,c.
// ---------------------------------------------------------------------------
__global__ __launch_bounds__(256) void cell1_k(
    const int* __restrict__ ids, const bf16* __restrict__ S,
    const float* __restrict__ Wiou, const float* __restrict__ biou,
    const float* __restrict__ Wf, const float* __restrict__ bfv,
    bf16* __restrict__ h_all, bf16* __restrict__ c_all,
    int m, int offAbs)
{
    int idx = blockIdx.x * 256 + threadIdx.x;
    if (idx >= m * 96) return;
    int i = idx / 96, j8 = (idx - i * 96) * 8;
    int g = offAbs + i;
    int id = ids[g];
    const bf16* s = S + (size_t)i * 3840 + j8;
    const float* w = Wiou + (size_t)id * 2304 + j8;
    const float* wf = Wf + (size_t)id * 768 + j8;
    bf16x8 si = *(const bf16x8*)(s);
    bf16x8 so = *(const bf16x8*)(s + 768);
    bf16x8 su = *(const bf16x8*)(s + 1536);
    bf16x8 s0 = *(const bf16x8*)(s + 2304);
    bf16x8 s1 = *(const bf16x8*)(s + 3072);
    bf16x8 cl = *(const bf16x8*)(c_all + (size_t)(2 * g + 1) * HD + j8);
    bf16x8 cr = *(const bf16x8*)(c_all + (size_t)(2 * g + 2) * HD + j8);
    bf16x8 hv, cv;
#pragma unroll
    for (int u = 0; u < 8; ++u) {
        float iv = sigm(sb(si[u]) + w[u] + biou[j8 + u]);
        float ov = sigm(sb(so[u]) + w[768 + u] + biou[768 + j8 + u]);
        float uv = tanhf(sb(su[u]) + w[1536 + u] + biou[1536 + j8 + u]);
        float xf = wf[u] + bfv[j8 + u];
        float f0 = sigm(sb(s0[u]) + xf);
        float f1 = sigm(sb(s1[u]) + xf);
        float c = iv * uv + f0 * sb(cl[u]) + f1 * sb(cr[u]);
        cv[u] = bs(c);
        hv[u] = bs(ov * tanhf(c));
    }
    *(bf16x8*)(h_all + (size_t)g * HD + j8) = hv;
    *(bf16x8*)(c_all + (size_t)g * HD + j8) = cv;
}

// ---------------------------------------------------------------------------
// Pass-2 cell, vectorized: bf16 S(m x 4608) -> h3.
// ---------------------------------------------------------------------------
__global__ __launch_bounds__(256) void cell2_k(
    const int* __restrict__ ids, const bf16* __restrict__ S,
    const float* __restrict__ Wiou, const float* __restrict__ biou,
    const float* __restrict__ Wf, const float* __restrict__ bfv,
    const bf16* __restrict__ c_all, bf16* __restrict__ h3_all,
    int m, int g0)
{
    int idx = blockIdx.x * 256 + threadIdx.x;
    if (idx >= m * 96) return;
    int i = idx / 96, j8 = (idx - i * 96) * 8;
    int g = g0 + i;
    int id = ids[g];
    const bf16* s = S + (size_t)i * 4608 + j8;
    const float* w = Wiou + (size_t)id * 2304 + j8;
    const float* wf = Wf + (size_t)id * 768 + j8;
    bf16x8 si = *(const bf16x8*)(s);
    bf16x8 so = *(const bf16x8*)(s + 768);
    bf16x8 su = *(const bf16x8*)(s + 1536);
    bf16x8 s0 = *(const bf16x8*)(s + 2304);
    bf16x8 s1 = *(const bf16x8*)(s + 3072);
    bf16x8 s2 = *(const bf16x8*)(s + 3840);
    bf16x8 cs = *(const bf16x8*)(c_all + (size_t)g * HD + j8);
    bf16x8 cl = *(const bf16x8*)(c_all + (size_t)(2 * g + 1) * HD + j8);
    bf16x8 cr = *(const bf16x8*)(c_all + (size_t)(2 * g + 2) * HD + j8);
    bf16x8 hv;
#pragma unroll
    for (int u = 0; u < 8; ++u) {
        float iv = sigm(sb(si[u]) + w[u] + biou[j8 + u]);
        float ov = sigm(sb(so[u]) + w[768 + u] + biou[768 + j8 + u]);
        float uv = tanhf(sb(su[u]) + w[1536 + u] + biou[1536 + j8 + u]);
        float xf = wf[u] + bfv[j8 + u];
        float f0 = sigm(sb(s0[u]) + xf);
        float f1 = sigm(sb(s1[u]) + xf);
        float f2 = sigm(sb(s2[u]) + xf);
        float c = iv * uv + f0 * sb(cs[u]) + f1 * sb(cl[u]) + f2 * sb(cr[u]);
        hv[u] = bs(ov * tanhf(c));
    }
    *(bf16x8*)(h3_all + (size_t)g * HD + j8) = hv;
}

// ---------------------------------------------------------------------------
// Head softmaxes from logits L[g][128] (0-1 hl, 2-3 int, 4-67 act). fp32 out.
// ---------------------------------------------------------------------------
__global__ __launch_bounds__(256) void hsm_k(
    const float* __restrict__ L, const int* __restrict__ mask,
    const float* __restrict__ hlb, const float* __restrict__ intb,
    const float* __restrict__ actb, float* __restrict__ out)
{
    int g = blockIdx.x * 4 + (threadIdx.x >> 6);
    if (g >= N_NODES) return;
    int t = threadIdx.x & 63;
    const float* lr = L + (size_t)g * 128;

    bool on = mask[(size_t)g * 64 + t] > 0;
    float x = (lr[4 + t] + actb[t]) * (1.0f / TEMP);
    float mx = on ? x : -INFINITY;
#pragma unroll
    for (int o = 32; o; o >>= 1) mx = fmaxf(mx, __shfl_xor(mx, o));
    float e = on ? __expf(x - mx) : 0.0f;
    float s = e;
#pragma unroll
    for (int o = 32; o; o >>= 1) s += __shfl_xor(s, o);
    float r = (s > 0.f) ? e / s : (1.0f / 64.0f);
    out[(size_t)g * 68 + 4 + t] = r;

    if (t == 0) {
        float a = (lr[0] + hlb[0]) * (1.0f / TEMP);
        float b = (lr[1] + hlb[1]) * (1.0f / TEMP);
        float m2 = fmaxf(a, b);
        float e0 = __expf(a - m2), e1 = __expf(b - m2);
        out[(size_t)g * 68 + 0] = e0 / (e0 + e1);
        out[(size_t)g * 68 + 1] = e1 / (e0 + e1);
    } else if (t == 1) {
        float a = (lr[2] + intb[0]) * (1.0f / TEMP);
        float b = (lr[3] + intb[1]) * (1.0f / TEMP);
        float m2 = fmaxf(a, b);
        float e0 = __expf(a - m2), e1 = __expf(b - m2);
        out[(size_t)g * 68 + 2] = e0 / (e0 + e1);
        out[(size_t)g * 68 + 3] = e1 / (e0 + e1);
    }
}

// ---------------------------------------------------------------------------
extern "C" void kernel_launch(void* const* d_in, const int* in_sizes, int n_in,
                              void* d_out, int out_size, void* d_ws, size_t ws_size,
                              hipStream_t stream)
{
    const int*   ids     = (const int*)d_in[0];
    const int*   mask    = (const int*)d_in[1];
    const float* Wb_iou  = (const float*)d_in[2];
    const float* Ub_iou  = (const float*)d_in[3];
    const float* bb_iou  = (const float*)d_in[4];
    const float* Wb_f    = (const float*)d_in[5];
    const float* Ub_f    = (const float*)d_in[6];
    const float* bb_f    = (const float*)d_in[7];
    const float* Wt_iou  = (const float*)d_in[8];
    const float* Ut_iou  = (const float*)d_in[9];
    const float* bt_iou  = (const float*)d_in[10];
    const float* Wt_f    = (const float*)d_in[11];
    const float* Ut_f    = (const float*)d_in[12];
    const float* bt_f    = (const float*)d_in[13];
    const float* ffn_W1  = (const float*)d_in[14];
    const float* ffn_b1  = (const float*)d_in[15];
    const float* ffn_W2  = (const float*)d_in[16];
    const float* ffn_b2  = (const float*)d_in[17];
    const float* hl_W    = (const float*)d_in[18];
    const float* hl_b    = (const float*)d_in[19];
    const float* int_W   = (const float*)d_in[20];
    const float* int_b   = (const float*)d_in[21];
    const float* act_W   = (const float*)d_in[22];
    const float* act_b   = (const float*)d_in[23];

    // ---- workspace layout (~187 MB) ----
    char* p = (char*)d_ws;
    bf16* h_all  = (bf16*)p; p += (size_t)NHF * 2;
    bf16* c_all  = (bf16*)p; p += (size_t)NHF * 2;
    bf16* h3_all = (bf16*)p; p += (size_t)NHF * 2;
    bf16* BT1 = (bf16*)p; p += (size_t)T1SZ * 2;
    bf16* BT2 = (bf16*)p; p += (size_t)T2SZ * 2;
    bf16* W1T = (bf16*)p; p += (size_t)WSZ * 2;
    bf16* W2T = (bf16*)p; p += (size_t)WSZ * 2;
    bf16* WhT = (bf16*)p; p += (size_t)HSZ * 2;
    bf16* Sb  = (bf16*)p;              // bf16 S: up to 8191 x 4608 = 75.5 MB
    bf16* t1  = c_all;                 // FFN hidden aliases dead c
    bf16* h4  = h_all;                 // FFN out aliases dead h
    float* Lg = (float*)h3_all;        // head logits alias dead h3 (8.4 MB)

    conv_k<<<(CONVTOT + 255) / 256, 256, 0, stream>>>(
        Ub_iou, Ub_f, Ut_iou, Ut_f, ffn_W1, ffn_W2, hl_W, int_W, act_W,
        BT1, BT2, W1T, W2T, WhT);

    leaf_k<<<(8192 * 96 + 255) / 256, 256, 0, stream>>>(
        ids, Wb_iou, bb_iou, Wt_iou, bt_iou, h_all, c_all, h3_all);

    // ---- pass 1: split mm+cell for n>=512, fused fmm for small levels ----
    for (int d = 12; d >= 0; --d) {
        int n = 1 << d;
        if (n >= 512) {
            int gy = n / 128;
            mm_k<3, 0><<<30 * gy, 256, 0, stream>>>(
                h_all + (size_t)(2 * n - 1) * HD, BT1, nullptr, Sb, nullptr,
                n, 3840, 1536, gy);
            cell1_k<<<(n * 96 + 255) / 256, 256, 0, stream>>>(
                ids, Sb, Wb_iou, bb_iou, Wb_f, bb_f, h_all, c_all, n, n - 1);
        } else {
            fmm_k<<<dim3(12, (n + 63) / 64), 256, 0, stream>>>(
                ids, h_all + (size_t)(2 * n - 1) * HD, BT1,
                Wb_iou, bb_iou, Wb_f, bb_f, c_all, h_all, c_all, n, n - 1);
        }
    }

    // ---- pass 2: single chunk, gather fused into GEMM ----
    mm_k<3, 1><<<36 * 64, 256, 0, stream>>>(
        h_all, BT2, nullptr, Sb, nullptr, NLEAF_OFF, 4608, 2304, 64);
    cell2_k<<<(NLEAF_OFF * 96 + 255) / 256, 256, 0, stream>>>(
        ids, Sb, Wt_iou, bt_iou, Wt_f, bt_f, c_all, h3_all, NLEAF_OFF, 0);

    // ---- FFN ----
    mm_k<1, 0><<<6 * 128, 256, 0, stream>>>(
        h3_all, W1T, nullptr, t1, ffn_b1, N_NODES, 768, 768, 128);
    mm_k<2, 0><<<6 * 128, 256, 0, stream>>>(
        t1, W2T, nullptr, h4, ffn_b2, N_NODES, 768, 768, 128);

    // ---- heads: logits GEMM + softmax ----
    mm_k<0, 0><<<1 * 128, 256, 0, stream>>>(
        h4, WhT, Lg, nullptr, nullptr, N_NODES, 128, 768, 128);
    hsm_k<<<(N_NODES + 3) / 4, 256, 0, stream>>>(
        Lg, mask, hl_b, int_b, act_b, (float*)d_out);
}

// Round 10
// 1323.444 us; speedup vs baseline: 1.0214x; 1.0214x over previous
//
#include <hip/hip_runtime.h>
#include <hip/hip_bf16.h>

#define HD 768
#define N_NODES 16383
#define NLEAF_OFF 8191     // first leaf node index (level d=13 offset)
#define NHF 12582144       // N_NODES * HD
#define TEMP 3.0f

using bf16 = __hip_bfloat16;
typedef __attribute__((ext_vector_type(8))) short bf16x8;
typedef __attribute__((ext_vector_type(4))) float f32x4;

__device__ __forceinline__ float sigm(float x) { return 1.0f / (1.0f + __expf(-x)); }
__device__ __forceinline__ float b2f(bf16 v)   { return __bfloat162float(v); }
__device__ __forceinline__ bf16  f2b(float v)  { return __float2bfloat16(v); }
__device__ __forceinline__ short bs(float v)   { bf16 t = f2b(v); return *(short*)&t; }
__device__ __forceinline__ float sb(short v)   { bf16 t = *(bf16*)&v; return b2f(t); }

// async global->LDS, 16B per lane. LDS dest = wave-uniform base + lane*16.
__device__ __forceinline__ void gload16(const void* g, void* l) {
    __builtin_amdgcn_global_load_lds(
        (const __attribute__((address_space(1))) unsigned int*)g,
        (__attribute__((address_space(3))) unsigned int*)l, 16, 0, 0);
}

// ---------------------------------------------------------------------------
// ONE fused weight-conversion kernel (bf16 B^T, gate-major layouts).
// ---------------------------------------------------------------------------
#define T1SZ 5898240      // 3840*1536
#define T2SZ 10616832     // 4608*2304
#define WSZ  589824       // 768*768
#define HSZ  98304        // 128*768
#define CONVTOT (T1SZ + T2SZ + 2*WSZ + HSZ)

__global__ __launch_bounds__(256) void conv_k(
    const float* __restrict__ Ub_iou, const float* __restrict__ Ub_f,
    const float* __restrict__ Ut_iou, const float* __restrict__ Ut_f,
    const float* __restrict__ ffn_W1, const float* __restrict__ ffn_W2,
    const float* __restrict__ hlW, const float* __restrict__ intW,
    const float* __restrict__ actW,
    bf16* __restrict__ BT1, bf16* __restrict__ BT2,
    bf16* __restrict__ W1T, bf16* __restrict__ W2T, bf16* __restrict__ WhT)
{
    int idx = blockIdx.x * 256 + threadIdx.x;
    if (idx >= CONVTOT) return;
    if (idx < T1SZ) {
        int n = idx / 1536, k = idx - n * 1536;
        int l = (k >= 768);
        int h = k - l * 768;
        float v;
        if (n < 2304) v = Ub_iou[(size_t)k * 2304 + n];
        else {
            int c2 = n - 2304;
            int kk = c2 / 768, o = c2 - kk * 768;
            v = Ub_f[(((size_t)(kk * 2 + l)) * 768 + h) * 768 + o];
        }
        BT1[idx] = f2b(v);
    } else if (idx < T1SZ + T2SZ) {
        int i2 = idx - T1SZ;
        int n = i2 / 2304, k = i2 - n * 2304;
        int l = (k >= 768) + (k >= 1536);
        int h = k - l * 768;
        float v;
        if (n < 2304) v = Ut_iou[(size_t)k * 2304 + n];
        else {
            int c2 = n - 2304;
            int kk = c2 / 768, o = c2 - kk * 768;
            v = Ut_f[(((size_t)(kk * 3 + l)) * 768 + h) * 768 + o];
        }
        BT2[i2] = f2b(v);
    } else if (idx < T1SZ + T2SZ + WSZ) {
        int i2 = idx - T1SZ - T2SZ;
        int n = i2 / 768, k = i2 - n * 768;
        W1T[i2] = f2b(ffn_W1[(size_t)k * 768 + n]);
    } else if (idx < T1SZ + T2SZ + 2 * WSZ) {
        int i2 = idx - T1SZ - T2SZ - WSZ;
        int n = i2 / 768, k = i2 - n * 768;
        W2T[i2] = f2b(ffn_W2[(size_t)k * 768 + n]);
    } else {
        int i2 = idx - T1SZ - T2SZ - 2 * WSZ;
        int n = i2 / 768, k = i2 - n * 768;
        float v = 0.f;
        if (n < 2)       v = hlW[(size_t)k * 2 + n];
        else if (n < 4)  v = intW[(size_t)k * 2 + (n - 2)];
        else if (n < 68) v = actW[(size_t)k * 64 + (n - 4)];
        WhT[i2] = f2b(v);
    }
}

// ---------------------------------------------------------------------------
// Fused leaf kernel, vectorized (8 j per thread): pass-1 h,c AND pass-2 h3.
// ---------------------------------------------------------------------------
__global__ __launch_bounds__(256) void leaf_k(
    const int* __restrict__ ids,
    const float* __restrict__ Wb, const float* __restrict__ bb,
    const float* __restrict__ Wt, const float* __restrict__ bt,
    bf16* __restrict__ h_all, bf16* __restrict__ c_all, bf16* __restrict__ h3_all)
{
    int idx = blockIdx.x * 256 + threadIdx.x;
    if (idx >= 8192 * 96) return;
    int i = idx / 96, j8 = (idx - i * 96) * 8;
    int g = NLEAF_OFF + i;
    int id = ids[g];
    const float* w  = Wb + (size_t)id * 2304 + j8;
    const float* w2 = Wt + (size_t)id * 2304 + j8;
    bf16x8 hv, cv, h3v;
#pragma unroll
    for (int u = 0; u < 8; ++u) {
        float iv = sigm(w[u] + bb[j8 + u]);
        float ov = sigm(w[768 + u] + bb[768 + j8 + u]);
        float gv = tanhf(w[1536 + u] + bb[1536 + j8 + u]);
        float c = iv * gv;
        hv[u] = bs(ov * tanhf(c));
        cv[u] = bs(c);
    }
#pragma unroll
    for (int u = 0; u < 8; ++u) {
        float iv = sigm(w2[u] + bt[j8 + u]);
        float ov = sigm(w2[768 + u] + bt[768 + j8 + u]);
        float gv = tanhf(w2[1536 + u] + bt[1536 + j8 + u]);
        float c = iv * gv;
        h3v[u] = bs(ov * tanhf(c));
    }
    *(bf16x8*)(h_all + (size_t)g * HD + j8) = hv;
    *(bf16x8*)(c_all + (size_t)g * HD + j8) = cv;
    *(bf16x8*)(h3_all + (size_t)g * HD + j8) = h3v;
}

// ---------------------------------------------------------------------------
// bf16 MFMA GEMM (R8-proven m97 structure): C[M x N] = A @ BT^T.
// 128x128 tile, 4 waves, BK=32, linear LDS [128][32], global_load_lds staging.
// GATHER=1 (pass 2): A row r = [h(r), h(2r+1), h(2r+2)] via per-lane sources.
// EPI 0: fp32 Cf. EPI 1: bias+relu bf16. EPI 2: bias bf16. EPI 3: plain bf16.
// ---------------------------------------------------------------------------
template <int EPI, int GATHER>
__global__ __launch_bounds__(256) void mm_k(
    const bf16* __restrict__ A, const bf16* __restrict__ BT,
    float* __restrict__ Cf, bf16* __restrict__ Cb,
    const float* __restrict__ bias,
    int M, int N, int K)
{
    __shared__ short As[128 * 32];
    __shared__ short Bs[128 * 32];

    int tid  = threadIdx.x;
    int lane = tid & 63;
    int wave = tid >> 6;
    int wr = wave >> 1, wc = wave & 1;
    int bx = blockIdx.x, by = blockIdx.y;

    f32x4 acc[4][4] = {};

    int sr  = lane >> 2;
    int sc8 = (lane & 3) * 8;
    int arow0 = by * 128 + wave * 16 + sr;
    int arow1 = arow0 + 64;
    if (arow0 > M - 1) arow0 = M - 1;
    if (arow1 > M - 1) arow1 = M - 1;
    const bf16* gA0 = A + (size_t)arow0 * K + sc8;
    const bf16* gA1 = A + (size_t)arow1 * K + sc8;
    const bf16* gB0 = BT + (size_t)(bx * 128 + wave * 16 + sr) * K + sc8;
    const bf16* gB1 = BT + (size_t)(bx * 128 + wave * 16 + sr + 64) * K + sc8;
    short* lA0 = As + wave * 512;
    short* lA1 = As + wave * 512 + 2048;
    short* lB0 = Bs + wave * 512;
    short* lB1 = Bs + wave * 512 + 2048;

    int fr = lane & 15;
    int fk = (lane >> 4) << 3;
    const short* pAf = As + (wr * 64 + fr) * 32 + fk;
    const short* pBf = Bs + (wc * 64 + fr) * 32 + fk;

    for (int kt = 0; kt < K; kt += 32) {
        if constexpr (GATHER) {
            int ch = (kt >= 768) + (kt >= 1536);
            int col = kt - ch * 768 + sc8;
            int n0 = (ch == 0) ? arow0 : (2 * arow0 + ch);
            int n1 = (ch == 0) ? arow1 : (2 * arow1 + ch);
            gload16(A + (size_t)n0 * HD + col, lA0);
            gload16(A + (size_t)n1 * HD + col, lA1);
        } else {
            gload16(gA0 + kt, lA0);
            gload16(gA1 + kt, lA1);
        }
        gload16(gB0 + kt, lB0);
        gload16(gB1 + kt, lB1);
        __syncthreads();

        bf16x8 a[4], b[4];
#pragma unroll
        for (int m = 0; m < 4; m++) a[m] = *(const bf16x8*)(pAf + m * 512);
#pragma unroll
        for (int n = 0; n < 4; n++) b[n] = *(const bf16x8*)(pBf + n * 512);
#pragma unroll
        for (int m = 0; m < 4; m++)
#pragma unroll
            for (int n = 0; n < 4; n++)
                acc[m][n] = __builtin_amdgcn_mfma_f32_16x16x32_bf16(
                    a[m], b[n], acc[m][n], 0, 0, 0);
        __syncthreads();
    }

    int rbase = by * 128 + wr * 64 + ((lane >> 4) << 2);
    int cbase = bx * 128 + wc * 64 + fr;
#pragma unroll
    for (int m = 0; m < 4; m++) {
#pragma unroll
        for (int r = 0; r < 4; r++) {
            int row = rbase + m * 16 + r;
            if (row >= M) continue;
#pragma unroll
            for (int n = 0; n < 4; n++) {
                int col = cbase + n * 16;
                float v = acc[m][n][r];
                if constexpr (EPI == 1) {
                    v = fmaxf(v + bias[col], 0.f);
                    Cb[(size_t)row * N + col] = f2b(v);
                } else if constexpr (EPI == 2) {
                    v = v + bias[col];
                    Cb[(size_t)row * N + col] = f2b(v);
                } else if constexpr (EPI == 3) {
                    Cb[(size_t)row * N + col] = f2b(v);
                } else {
                    Cf[(size_t)row * N + col] = v;
                }
            }
        }
    }
}

// ---------------------------------------------------------------------------
// FUSED small-level kernel (pass 1, n < 512). 64x64x5-gate tile, BK=32.
// (R8-proven version.)
// ---------------------------------------------------------------------------
__global__ __launch_bounds__(256) void fmm_k(
    const int* __restrict__ ids,
    const bf16* __restrict__ Abase,
    const bf16* __restrict__ BT,
    const float* __restrict__ Wiou, const float* __restrict__ biou,
    const float* __restrict__ Wf, const float* __restrict__ bfv,
    const bf16* __restrict__ c_all,
    bf16* __restrict__ h_out, bf16* __restrict__ c_out,
    int M, int off)
{
    constexpr int NG = 5;
    constexpr int K  = 1536;
    __shared__ short As[64 * 32];
    __shared__ short Bs[NG * 64 * 32];

    int tid  = threadIdx.x;
    int lane = tid & 63;
    int wave = tid >> 6;
    int wr = wave >> 1, wc = wave & 1;
    int bx = blockIdx.x, by = blockIdx.y;

    f32x4 acc[NG][2][2] = {};

    int sr  = lane >> 2;
    int sc8 = (lane & 3) * 8;
    int arow = by * 64 + wave * 16 + sr;
    if (arow > M - 1) arow = M - 1;

    const bf16* gB[NG];
    short* lB[NG];
#pragma unroll
    for (int t = 0; t < NG; ++t) {
        int s = wave + 4 * t;
        int gb = s >> 2, q = s & 3;
        gB[t] = BT + (size_t)(gb * 768 + bx * 64 + q * 16 + sr) * K + sc8;
        lB[t] = Bs + gb * 2048 + q * 512;
    }
    short* lA = As + wave * 512;
    const bf16* gA1 = Abase + (size_t)arow * 1536 + sc8;

    int fr = lane & 15;
    int fk = (lane >> 4) << 3;
    const short* pA = As + (wr * 32 + fr) * 32 + fk;
    const short* pB = Bs + (wc * 32 + fr) * 32 + fk;

    for (int kt = 0; kt < K; kt += 32) {
        gload16(gA1 + kt, lA);
#pragma unroll
        for (int t = 0; t < NG; ++t) gload16(gB[t] + kt, lB[t]);
        __syncthreads();

        bf16x8 a0 = *(const bf16x8*)pA;
        bf16x8 a1 = *(const bf16x8*)(pA + 512);
#pragma unroll
        for (int g = 0; g < NG; ++g) {
            bf16x8 b0 = *(const bf16x8*)(pB + g * 2048);
            bf16x8 b1 = *(const bf16x8*)(pB + g * 2048 + 512);
            acc[g][0][0] = __builtin_amdgcn_mfma_f32_16x16x32_bf16(a0, b0, acc[g][0][0], 0, 0, 0);
            acc[g][0][1] = __builtin_amdgcn_mfma_f32_16x16x32_bf16(a0, b1, acc[g][0][1], 0, 0, 0);
            acc[g][1][0] = __builtin_amdgcn_mfma_f32_16x16x32_bf16(a1, b0, acc[g][1][0], 0, 0, 0);
            acc[g][1][1] = __builtin_amdgcn_mfma_f32_16x16x32_bf16(a1, b1, acc[g][1][1], 0, 0, 0);
        }
        __syncthreads();
    }

    int lr4 = (lane >> 4) << 2;
    int c0  = bx * 64 + wc * 32 + fr;
#pragma unroll
    for (int m = 0; m < 2; ++m) {
#pragma unroll
        for (int r = 0; r < 4; ++r) {
            int row = by * 64 + wr * 32 + m * 16 + lr4 + r;
            if (row >= M) continue;
            int g = off + row;
            int id = ids[g];
            const float* wi = Wiou + (size_t)id * 2304;
            const float* wf = Wf + (size_t)id * 768;
#pragma unroll
            for (int n = 0; n < 2; ++n) {
                int j = c0 + n * 16;
                float iv = sigm(acc[0][m][n][r] + wi[j] + biou[j]);
                float ov = sigm(acc[1][m][n][r] + wi[768 + j] + biou[768 + j]);
                float uv = tanhf(acc[2][m][n][r] + wi[1536 + j] + biou[1536 + j]);
                float xf = wf[j] + bfv[j];
                float f0 = sigm(acc[3][m][n][r] + xf);
                float f1 = sigm(acc[4][m][n][r] + xf);
                float cv = iv * uv
                         + f0 * b2f(c_all[(size_t)(2 * g + 1) * HD + j])
                         + f1 * b2f(c_all[(size_t)(2 * g + 2) * HD + j]);
                c_out[(size_t)g * HD + j] = f2b(cv);
                h_out[(size_t)g * HD + j] = f2b(ov * tanhf(cv));
            }
        }
    }
}

// ---------------------------------------------------------------------------
// Pass-1 cell, vectorized (8 j per thread): bf16 S(m x 3840) -> h,c.
// ---------------------------------------------------------------------------
__global__ __launch_bounds__(256) void cell1_k(
    const int* __restrict__ ids, const bf16* __restrict__ S,
    const float* __restrict__ Wiou, const float* __restrict__ biou,
    const float* __restrict__ Wf, const float* __restrict__ bfv,
    bf16* __restrict__ h_all, bf16* __restrict__ c_all,
    int m, int offAbs)
{
    int idx = blockIdx.x * 256 + threadIdx.x;
    if (idx >= m * 96) return;
    int i = idx / 96, j8 = (idx - i * 96) * 8;
    int g = offAbs + i;
    int id = ids[g];
    const bf16* s = S + (size_t)i * 3840 + j8;
    const float* w = Wiou + (size_t)id * 2304 + j8;
    const float* wf = Wf + (size_t)id * 768 + j8;
    bf16x8 si = *(const bf16x8*)(s);
    bf16x8 so = *(const bf16x8*)(s + 768);
    bf16x8 su = *(const bf16x8*)(s + 1536);
    bf16x8 s0 = *(const bf16x8*)(s + 2304);
    bf16x8 s1 = *(const bf16x8*)(s + 3072);
    bf16x8 cl = *(const bf16x8*)(c_all + (size_t)(2 * g + 1) * HD + j8);
    bf16x8 cr = *(const bf16x8*)(c_all + (size_t)(2 * g + 2) * HD + j8);
    bf16x8 hv, cv;
#pragma unroll
    for (int u = 0; u < 8; ++u) {
        float iv = sigm(sb(si[u]) + w[u] + biou[j8 + u]);
        float ov = sigm(sb(so[u]) + w[768 + u] + biou[768 + j8 + u]);
        float uv = tanhf(sb(su[u]) + w[1536 + u] + biou[1536 + j8 + u]);
        float xf = wf[u] + bfv[j8 + u];
        float f0 = sigm(sb(s0[u]) + xf);
        float f1 = sigm(sb(s1[u]) + xf);
        float c = iv * uv + f0 * sb(cl[u]) + f1 * sb(cr[u]);
        cv[u] = bs(c);
        hv[u] = bs(ov * tanhf(c));
    }
    *(bf16x8*)(h_all + (size_t)g * HD + j8) = hv;
    *(bf16x8*)(c_all + (size_t)g * HD + j8) = cv;
}

// ---------------------------------------------------------------------------
// Pass-2 cell, vectorized: bf16 S(m x 4608) -> h3.
// ---------------------------------------------------------------------------
__global__ __launch_bounds__(256) void cell2_k(
    const int* __restrict__ ids, const bf16* __restrict__ S,
    const float* __restrict__ Wiou, const float* __restrict__ biou,
    const float* __restrict__ Wf, const float* __restrict__ bfv,
    const bf16* __restrict__ c_all, bf16* __restrict__ h3_all,
    int m, int g0)
{
    int idx = blockIdx.x * 256 + threadIdx.x;
    if (idx >= m * 96) return;
    int i = idx / 96, j8 = (idx - i * 96) * 8;
    int g = g0 + i;
    int id = ids[g];
    const bf16* s = S + (size_t)i * 4608 + j8;
    const float* w = Wiou + (size_t)id * 2304 + j8;
    const float* wf = Wf + (size_t)id * 768 + j8;
    bf16x8 si = *(const bf16x8*)(s);
    bf16x8 so = *(const bf16x8*)(s + 768);
    bf16x8 su = *(const bf16x8*)(s + 1536);
    bf16x8 s0 = *(const bf16x8*)(s + 2304);
    bf16x8 s1 = *(const bf16x8*)(s + 3072);
    bf16x8 s2 = *(const bf16x8*)(s + 3840);
    bf16x8 cs = *(const bf16x8*)(c_all + (size_t)g * HD + j8);
    bf16x8 cl = *(const bf16x8*)(c_all + (size_t)(2 * g + 1) * HD + j8);
    bf16x8 cr = *(const bf16x8*)(c_all + (size_t)(2 * g + 2) * HD + j8);
    bf16x8 hv;
#pragma unroll
    for (int u = 0; u < 8; ++u) {
        float iv = sigm(sb(si[u]) + w[u] + biou[j8 + u]);
        float ov = sigm(sb(so[u]) + w[768 + u] + biou[768 + j8 + u]);
        float uv = tanhf(sb(su[u]) + w[1536 + u] + biou[1536 + j8 + u]);
        float xf = wf[u] + bfv[j8 + u];
        float f0 = sigm(sb(s0[u]) + xf);
        float f1 = sigm(sb(s1[u]) + xf);
        float f2 = sigm(sb(s2[u]) + xf);
        float c = iv * uv + f0 * sb(cs[u]) + f1 * sb(cl[u]) + f2 * sb(cr[u]);
        hv[u] = bs(ov * tanhf(c));
    }
    *(bf16x8*)(h3_all + (size_t)g * HD + j8) = hv;
}

// ---------------------------------------------------------------------------
// Head softmaxes from logits L[g][128] (0-1 hl, 2-3 int, 4-67 act). fp32 out.
// ---------------------------------------------------------------------------
__global__ __launch_bounds__(256) void hsm_k(
    const float* __restrict__ L, const int* __restrict__ mask,
    const float* __restrict__ hlb, const float* __restrict__ intb,
    const float* __restrict__ actb, float* __restrict__ out)
{
    int g = blockIdx.x * 4 + (threadIdx.x >> 6);
    if (g >= N_NODES) return;
    int t = threadIdx.x & 63;
    const float* lr = L + (size_t)g * 128;

    bool on = mask[(size_t)g * 64 + t] > 0;
    float x = (lr[4 + t] + actb[t]) * (1.0f / TEMP);
    float mx = on ? x : -INFINITY;
#pragma unroll
    for (int o = 32; o; o >>= 1) mx = fmaxf(mx, __shfl_xor(mx, o));
    float e = on ? __expf(x - mx) : 0.0f;
    float s = e;
#pragma unroll
    for (int o = 32; o; o >>= 1) s += __shfl_xor(s, o);
    float r = (s > 0.f) ? e / s : (1.0f / 64.0f);
    out[(size_t)g * 68 + 4 + t] = r;

    if (t == 0) {
        float a = (lr[0] + hlb[0]) * (1.0f / TEMP);
        float b = (lr[1] + hlb[1]) * (1.0f / TEMP);
        float m2 = fmaxf(a, b);
        float e0 = __expf(a - m2), e1 = __expf(b - m2);
        out[(size_t)g * 68 + 0] = e0 / (e0 + e1);
        out[(size_t)g * 68 + 1] = e1 / (e0 + e1);
    } else if (t == 1) {
        float a = (lr[2] + intb[0]) * (1.0f / TEMP);
        float b = (lr[3] + intb[1]) * (1.0f / TEMP);
        float m2 = fmaxf(a, b);
        float e0 = __expf(a - m2), e1 = __expf(b - m2);
        out[(size_t)g * 68 + 2] = e0 / (e0 + e1);
        out[(size_t)g * 68 + 3] = e1 / (e0 + e1);
    }
}

// ---------------------------------------------------------------------------
extern "C" void kernel_launch(void* const* d_in, const int* in_sizes, int n_in,
                              void* d_out, int out_size, void* d_ws, size_t ws_size,
                              hipStream_t stream)
{
    const int*   ids     = (const int*)d_in[0];
    const int*   mask    = (const int*)d_in[1];
    const float* Wb_iou  = (const float*)d_in[2];
    const float* Ub_iou  = (const float*)d_in[3];
    const float* bb_iou  = (const float*)d_in[4];
    const float* Wb_f    = (const float*)d_in[5];
    const float* Ub_f    = (const float*)d_in[6];
    const float* bb_f    = (const float*)d_in[7];
    const float* Wt_iou  = (const float*)d_in[8];
    const float* Ut_iou  = (const float*)d_in[9];
    const float* bt_iou  = (const float*)d_in[10];
    const float* Wt_f    = (const float*)d_in[11];
    const float* Ut_f    = (const float*)d_in[12];
    const float* bt_f    = (const float*)d_in[13];
    const float* ffn_W1  = (const float*)d_in[14];
    const float* ffn_b1  = (const float*)d_in[15];
    const float* ffn_W2  = (const float*)d_in[16];
    const float* ffn_b2  = (const float*)d_in[17];
    const float* hl_W    = (const float*)d_in[18];
    const float* hl_b    = (const float*)d_in[19];
    const float* int_W   = (const float*)d_in[20];
    const float* int_b   = (const float*)d_in[21];
    const float* act_W   = (const float*)d_in[22];
    const float* act_b   = (const float*)d_in[23];

    // ---- workspace layout (~187 MB) ----
    char* p = (char*)d_ws;
    bf16* h_all  = (bf16*)p; p += (size_t)NHF * 2;
    bf16* c_all  = (bf16*)p; p += (size_t)NHF * 2;
    bf16* h3_all = (bf16*)p; p += (size_t)NHF * 2;
    bf16* BT1 = (bf16*)p; p += (size_t)T1SZ * 2;
    bf16* BT2 = (bf16*)p; p += (size_t)T2SZ * 2;
    bf16* W1T = (bf16*)p; p += (size_t)WSZ * 2;
    bf16* W2T = (bf16*)p; p += (size_t)WSZ * 2;
    bf16* WhT = (bf16*)p; p += (size_t)HSZ * 2;
    bf16* Sb  = (bf16*)p;              // bf16 S: up to 8191 x 4608 = 75.5 MB
    bf16* t1  = c_all;                 // FFN hidden aliases dead c
    bf16* h4  = h_all;                 // FFN out aliases dead h
    float* Lg = (float*)h3_all;        // head logits alias dead h3 (8.4 MB)

    conv_k<<<(CONVTOT + 255) / 256, 256, 0, stream>>>(
        Ub_iou, Ub_f, Ut_iou, Ut_f, ffn_W1, ffn_W2, hl_W, int_W, act_W,
        BT1, BT2, W1T, W2T, WhT);

    leaf_k<<<(8192 * 96 + 255) / 256, 256, 0, stream>>>(
        ids, Wb_iou, bb_iou, Wt_iou, bt_iou, h_all, c_all, h3_all);

    // ---- pass 1: split mm+cell for n>=512, fused fmm for small levels ----
    for (int d = 12; d >= 0; --d) {
        int n = 1 << d;
        if (n >= 512) {
            mm_k<3, 0><<<dim3(30, n / 128), 256, 0, stream>>>(
                h_all + (size_t)(2 * n - 1) * HD, BT1, nullptr, Sb, nullptr,
                n, 3840, 1536);
            cell1_k<<<(n * 96 + 255) / 256, 256, 0, stream>>>(
                ids, Sb, Wb_iou, bb_iou, Wb_f, bb_f, h_all, c_all, n, n - 1);
        } else {
            fmm_k<<<dim3(12, (n + 63) / 64), 256, 0, stream>>>(
                ids, h_all + (size_t)(2 * n - 1) * HD, BT1,
                Wb_iou, bb_iou, Wb_f, bb_f, c_all, h_all, c_all, n, n - 1);
        }
    }

    // ---- pass 2: single chunk, gather fused into GEMM ----
    mm_k<3, 1><<<dim3(36, 64), 256, 0, stream>>>(
        h_all, BT2, nullptr, Sb, nullptr, NLEAF_OFF, 4608, 2304);
    cell2_k<<<(NLEAF_OFF * 96 + 255) / 256, 256, 0, stream>>>(
        ids, Sb, Wt_iou, bt_iou, Wt_f, bt_f, c_all, h3_all, NLEAF_OFF, 0);

    // ---- FFN ----
    mm_k<1, 0><<<dim3(6, 128), 256, 0, stream>>>(
        h3_all, W1T, nullptr, t1, ffn_b1, N_NODES, 768, 768);
    mm_k<2, 0><<<dim3(6, 128), 256, 0, stream>>>(
        t1, W2T, nullptr, h4, ffn_b2, N_NODES, 768, 768);

    // ---- heads: logits GEMM + softmax ----
    mm_k<0, 0><<<dim3(1, 128), 256, 0, stream>>>(
        h4, WhT, Lg, nullptr, nullptr, N_NODES, 128, 768);
    hsm_k<<<(N_NODES + 3) / 4, 256, 0, stream>>>(
        Lg, mask, hl_b, int_b, act_b, (float*)d_out);
}

// Round 11
// 1141.732 us; speedup vs baseline: 1.1839x; 1.1592x over previous
//
#include <hip/hip_runtime.h>
#include <hip/hip_bf16.h>

#define HD 768
#define N_NODES 16383
#define NLEAF_OFF 8191     // first leaf node index (level d=13 offset)
#define NHF 12582144       // N_NODES * HD
#define TEMP 3.0f

using bf16 = __hip_bfloat16;
typedef __attribute__((ext_vector_type(8))) short bf16x8;
typedef __attribute__((ext_vector_type(4))) float f32x4;

__device__ __forceinline__ float sigm(float x) { return 1.0f / (1.0f + __expf(-x)); }
__device__ __forceinline__ float b2f(bf16 v)   { return __bfloat162float(v); }
__device__ __forceinline__ bf16  f2b(float v)  { return __float2bfloat16(v); }

// async global->LDS, 16B per lane. LDS dest = wave-uniform base + lane*16.
__device__ __forceinline__ void gload16(const void* g, void* l) {
    __builtin_amdgcn_global_load_lds(
        (const __attribute__((address_space(1))) unsigned int*)g,
        (__attribute__((address_space(3))) unsigned int*)l, 16, 0, 0);
}

// ---------------------------------------------------------------------------
// Fused weight-conversion kernel (bf16 B^T, gate-major layouts): BT1, BT2, W1T.
// ---------------------------------------------------------------------------
#define T1SZ 5898240      // 3840*1536
#define T2SZ 10616832     // 4608*2304
#define WSZ  589824       // 768*768
#define CONVTOT (T1SZ + T2SZ + WSZ)

__global__ __launch_bounds__(256) void conv_k(
    const float* __restrict__ Ub_iou, const float* __restrict__ Ub_f,
    const float* __restrict__ Ut_iou, const float* __restrict__ Ut_f,
    const float* __restrict__ ffn_W1,
    bf16* __restrict__ BT1, bf16* __restrict__ BT2, bf16* __restrict__ W1T)
{
    int idx = blockIdx.x * 256 + threadIdx.x;
    if (idx >= CONVTOT) return;
    if (idx < T1SZ) {
        int n = idx / 1536, k = idx - n * 1536;
        int l = (k >= 768);
        int h = k - l * 768;
        float v;
        if (n < 2304) v = Ub_iou[(size_t)k * 2304 + n];
        else {
            int c2 = n - 2304;
            int kk = c2 / 768, o = c2 - kk * 768;
            v = Ub_f[(((size_t)(kk * 2 + l)) * 768 + h) * 768 + o];
        }
        BT1[idx] = f2b(v);
    } else if (idx < T1SZ + T2SZ) {
        int i2 = idx - T1SZ;
        int n = i2 / 2304, k = i2 - n * 2304;
        int l = (k >= 768) + (k >= 1536);
        int h = k - l * 768;
        float v;
        if (n < 2304) v = Ut_iou[(size_t)k * 2304 + n];
        else {
            int c2 = n - 2304;
            int kk = c2 / 768, o = c2 - kk * 768;
            v = Ut_f[(((size_t)(kk * 3 + l)) * 768 + h) * 768 + o];
        }
        BT2[i2] = f2b(v);
    } else {
        int i2 = idx - T1SZ - T2SZ;
        int n = i2 / 768, k = i2 - n * 768;
        W1T[i2] = f2b(ffn_W1[(size_t)k * 768 + n]);
    }
}

// ---------------------------------------------------------------------------
// Folded head weights: WcT[n][k] = sum_j W2[k][j] * Wh[j][n] (fp32 dot -> bf16)
// where Wh cols: 0-1 hlW, 2-3 intW, 4-67 actW, 68-127 zero.
// bc[n] = sum_j b2[j]*Wh[j][n] + head_bias(n). One block per n (128 blocks).
// ---------------------------------------------------------------------------
__global__ __launch_bounds__(256) void convC_k(
    const float* __restrict__ W2, const float* __restrict__ b2,
    const float* __restrict__ hlW, const float* __restrict__ hlb,
    const float* __restrict__ intW, const float* __restrict__ intb,
    const float* __restrict__ actW, const float* __restrict__ actb,
    bf16* __restrict__ WcT, float* __restrict__ bc)
{
    int n = blockIdx.x;
    int t = threadIdx.x;
    __shared__ float wh[768];
    __shared__ float red[256];

    for (int j = t; j < 768; j += 256) {
        float v = 0.f;
        if (n < 2)       v = hlW[(size_t)j * 2 + n];
        else if (n < 4)  v = intW[(size_t)j * 2 + (n - 2)];
        else if (n < 68) v = actW[(size_t)j * 64 + (n - 4)];
        wh[j] = v;
    }
    __syncthreads();

    for (int k = t; k < 768; k += 256) {
        const float* w2r = W2 + (size_t)k * 768;
        float a0 = 0.f, a1 = 0.f, a2 = 0.f, a3 = 0.f;
        for (int j = 0; j < 768; j += 4) {
            a0 = fmaf(w2r[j],     wh[j],     a0);
            a1 = fmaf(w2r[j + 1], wh[j + 1], a1);
            a2 = fmaf(w2r[j + 2], wh[j + 2], a2);
            a3 = fmaf(w2r[j + 3], wh[j + 3], a3);
        }
        WcT[(size_t)n * 768 + k] = f2b(((a0 + a1) + (a2 + a3)));
    }

    float part = 0.f;
    for (int j = t; j < 768; j += 256) part = fmaf(b2[j], wh[j], part);
    red[t] = part;
    __syncthreads();
    if (t < 128) { red[t] += red[t + 128]; } __syncthreads();
    if (t < 64)  { red[t] += red[t + 64];  } __syncthreads();
    if (t == 0) {
        float s = 0.f;
        for (int u = 0; u < 64; ++u) s += red[u];
        float hb = 0.f;
        if (n < 2)       hb = hlb[n];
        else if (n < 4)  hb = intb[n - 2];
        else if (n < 68) hb = actb[n - 4];
        bc[n] = s + hb;
    }
}

// ---------------------------------------------------------------------------
// Fused leaf kernel (R8 scalar form): pass-1 h,c AND pass-2 h3.
// ---------------------------------------------------------------------------
__global__ __launch_bounds__(256) void leaf_k(
    const int* __restrict__ ids,
    const float* __restrict__ Wb, const float* __restrict__ bb,
    const float* __restrict__ Wt, const float* __restrict__ bt,
    bf16* __restrict__ h_all, bf16* __restrict__ c_all, bf16* __restrict__ h3_all)
{
    int idx = blockIdx.x * blockDim.x + threadIdx.x;
    if (idx >= 8192 * HD) return;
    int i = idx / HD, j = idx - i * HD;
    int g = NLEAF_OFF + i;
    int id = ids[g];
    const float* w = Wb + (size_t)id * 3 * HD;
    float iv = sigm(w[j] + bb[j]);
    float ov = sigm(w[HD + j] + bb[HD + j]);
    float gv = tanhf(w[2 * HD + j] + bb[2 * HD + j]);
    float c = iv * gv;
    h_all[(size_t)g * HD + j] = f2b(ov * tanhf(c));
    c_all[(size_t)g * HD + j] = f2b(c);

    const float* w2 = Wt + (size_t)id * 3 * HD;
    float iv2 = sigm(w2[j] + bt[j]);
    float ov2 = sigm(w2[HD + j] + bt[HD + j]);
    float gv2 = tanhf(w2[2 * HD + j] + bt[2 * HD + j]);
    float c2 = iv2 * gv2;
    h3_all[(size_t)g * HD + j] = f2b(ov2 * tanhf(c2));
}

// ---------------------------------------------------------------------------
// bf16 MFMA GEMM (R8-proven m97 structure): C[M x N] = A @ BT^T.
// 128x128 tile, 4 waves, BK=32, linear LDS [128][32], global_load_lds staging.
// GATHER=1 (pass 2): A row r = [h(r), h(2r+1), h(2r+2)] via per-lane sources.
// EPI 0: fp32 Cf. EPI 1: bias+relu bf16. EPI 3: plain bf16.
// ---------------------------------------------------------------------------
template <int EPI, int GATHER>
__global__ __launch_bounds__(256) void mm_k(
    const bf16* __restrict__ A, const bf16* __restrict__ BT,
    float* __restrict__ Cf, bf16* __restrict__ Cb,
    const float* __restrict__ bias,
    int M, int N, int K)
{
    __shared__ short As[128 * 32];
    __shared__ short Bs[128 * 32];

    int tid  = threadIdx.x;
    int lane = tid & 63;
    int wave = tid >> 6;
    int wr = wave >> 1, wc = wave & 1;
    int bx = blockIdx.x, by = blockIdx.y;

    f32x4 acc[4][4] = {};

    int sr  = lane >> 2;
    int sc8 = (lane & 3) * 8;
    int arow0 = by * 128 + wave * 16 + sr;
    int arow1 = arow0 + 64;
    if (arow0 > M - 1) arow0 = M - 1;
    if (arow1 > M - 1) arow1 = M - 1;
    const bf16* gA0 = A + (size_t)arow0 * K + sc8;
    const bf16* gA1 = A + (size_t)arow1 * K + sc8;
    const bf16* gB0 = BT + (size_t)(bx * 128 + wave * 16 + sr) * K + sc8;
    const bf16* gB1 = BT + (size_t)(bx * 128 + wave * 16 + sr + 64) * K + sc8;
    short* lA0 = As + wave * 512;
    short* lA1 = As + wave * 512 + 2048;
    short* lB0 = Bs + wave * 512;
    short* lB1 = Bs + wave * 512 + 2048;

    int fr = lane & 15;
    int fk = (lane >> 4) << 3;
    const short* pAf = As + (wr * 64 + fr) * 32 + fk;
    const short* pBf = Bs + (wc * 64 + fr) * 32 + fk;

    for (int kt = 0; kt < K; kt += 32) {
        if constexpr (GATHER) {
            int ch = (kt >= 768) + (kt >= 1536);
            int col = kt - ch * 768 + sc8;
            int n0 = (ch == 0) ? arow0 : (2 * arow0 + ch);
            int n1 = (ch == 0) ? arow1 : (2 * arow1 + ch);
            gload16(A + (size_t)n0 * HD + col, lA0);
            gload16(A + (size_t)n1 * HD + col, lA1);
        } else {
            gload16(gA0 + kt, lA0);
            gload16(gA1 + kt, lA1);
        }
        gload16(gB0 + kt, lB0);
        gload16(gB1 + kt, lB1);
        __syncthreads();

        bf16x8 a[4], b[4];
#pragma unroll
        for (int m = 0; m < 4; m++) a[m] = *(const bf16x8*)(pAf + m * 512);
#pragma unroll
        for (int n = 0; n < 4; n++) b[n] = *(const bf16x8*)(pBf + n * 512);
#pragma unroll
        for (int m = 0; m < 4; m++)
#pragma unroll
            for (int n = 0; n < 4; n++)
                acc[m][n] = __builtin_amdgcn_mfma_f32_16x16x32_bf16(
                    a[m], b[n], acc[m][n], 0, 0, 0);
        __syncthreads();
    }

    int rbase = by * 128 + wr * 64 + ((lane >> 4) << 2);
    int cbase = bx * 128 + wc * 64 + fr;
#pragma unroll
    for (int m = 0; m < 4; m++) {
#pragma unroll
        for (int r = 0; r < 4; r++) {
            int row = rbase + m * 16 + r;
            if (row >= M) continue;
#pragma unroll
            for (int n = 0; n < 4; n++) {
                int col = cbase + n * 16;
                float v = acc[m][n][r];
                if constexpr (EPI == 1) {
                    v = fmaxf(v + bias[col], 0.f);
                    Cb[(size_t)row * N + col] = f2b(v);
                } else if constexpr (EPI == 3) {
                    Cb[(size_t)row * N + col] = f2b(v);
                } else {
                    Cf[(size_t)row * N + col] = v;
                }
            }
        }
    }
}

// ---------------------------------------------------------------------------
// FUSED small-level kernel (pass 1, n < 512). 64x64x5-gate tile, BK=32.
// ---------------------------------------------------------------------------
__global__ __launch_bounds__(256) void fmm_k(
    const int* __restrict__ ids,
    const bf16* __restrict__ Abase,
    const bf16* __restrict__ BT,
    const float* __restrict__ Wiou, const float* __restrict__ biou,
    const float* __restrict__ Wf, const float* __restrict__ bfv,
    const bf16* __restrict__ c_all,
    bf16* __restrict__ h_out, bf16* __restrict__ c_out,
    int M, int off)
{
    constexpr int NG = 5;
    constexpr int K  = 1536;
    __shared__ short As[64 * 32];
    __shared__ short Bs[NG * 64 * 32];

    int tid  = threadIdx.x;
    int lane = tid & 63;
    int wave = tid >> 6;
    int wr = wave >> 1, wc = wave & 1;
    int bx = blockIdx.x, by = blockIdx.y;

    f32x4 acc[NG][2][2] = {};

    int sr  = lane >> 2;
    int sc8 = (lane & 3) * 8;
    int arow = by * 64 + wave * 16 + sr;
    if (arow > M - 1) arow = M - 1;

    const bf16* gB[NG];
    short* lB[NG];
#pragma unroll
    for (int t = 0; t < NG; ++t) {
        int s = wave + 4 * t;
        int gb = s >> 2, q = s & 3;
        gB[t] = BT + (size_t)(gb * 768 + bx * 64 + q * 16 + sr) * K + sc8;
        lB[t] = Bs + gb * 2048 + q * 512;
    }
    short* lA = As + wave * 512;
    const bf16* gA1 = Abase + (size_t)arow * 1536 + sc8;

    int fr = lane & 15;
    int fk = (lane >> 4) << 3;
    const short* pA = As + (wr * 32 + fr) * 32 + fk;
    const short* pB = Bs + (wc * 32 + fr) * 32 + fk;

    for (int kt = 0; kt < K; kt += 32) {
        gload16(gA1 + kt, lA);
#pragma unroll
        for (int t = 0; t < NG; ++t) gload16(gB[t] + kt, lB[t]);
        __syncthreads();

        bf16x8 a0 = *(const bf16x8*)pA;
        bf16x8 a1 = *(const bf16x8*)(pA + 512);
#pragma unroll
        for (int g = 0; g < NG; ++g) {
            bf16x8 b0 = *(const bf16x8*)(pB + g * 2048);
            bf16x8 b1 = *(const bf16x8*)(pB + g * 2048 + 512);
            acc[g][0][0] = __builtin_amdgcn_mfma_f32_16x16x32_bf16(a0, b0, acc[g][0][0], 0, 0, 0);
            acc[g][0][1] = __builtin_amdgcn_mfma_f32_16x16x32_bf16(a0, b1, acc[g][0][1], 0, 0, 0);
            acc[g][1][0] = __builtin_amdgcn_mfma_f32_16x16x32_bf16(a1, b0, acc[g][1][0], 0, 0, 0);
            acc[g][1][1] = __builtin_amdgcn_mfma_f32_16x16x32_bf16(a1, b1, acc[g][1][1], 0, 0, 0);
        }
        __syncthreads();
    }

    int lr4 = (lane >> 4) << 2;
    int c0  = bx * 64 + wc * 32 + fr;
#pragma unroll
    for (int m = 0; m < 2; ++m) {
#pragma unroll
        for (int r = 0; r < 4; ++r) {
            int row = by * 64 + wr * 32 + m * 16 + lr4 + r;
            if (row >= M) continue;
            int g = off + row;
            int id = ids[g];
            const float* wi = Wiou + (size_t)id * 2304;
            const float* wf = Wf + (size_t)id * 768;
#pragma unroll
            for (int n = 0; n < 2; ++n) {
                int j = c0 + n * 16;
                float iv = sigm(acc[0][m][n][r] + wi[j] + biou[j]);
                float ov = sigm(acc[1][m][n][r] + wi[768 + j] + biou[768 + j]);
                float uv = tanhf(acc[2][m][n][r] + wi[1536 + j] + biou[1536 + j]);
                float xf = wf[j] + bfv[j];
                float f0 = sigm(acc[3][m][n][r] + xf);
                float f1 = sigm(acc[4][m][n][r] + xf);
                float cv = iv * uv
                         + f0 * b2f(c_all[(size_t)(2 * g + 1) * HD + j])
                         + f1 * b2f(c_all[(size_t)(2 * g + 2) * HD + j]);
                c_out[(size_t)g * HD + j] = f2b(cv);
                h_out[(size_t)g * HD + j] = f2b(ov * tanhf(cv));
            }
        }
    }
}

// ---------------------------------------------------------------------------
// Pass-1 cell (R8 scalar form): bf16 S(m x 3840) -> bf16 h,c.
// ---------------------------------------------------------------------------
__global__ __launch_bounds__(256) void cell1_k(
    const int* __restrict__ ids, const bf16* __restrict__ S,
    const float* __restrict__ Wiou, const float* __restrict__ biou,
    const float* __restrict__ Wf, const float* __restrict__ bfv,
    bf16* __restrict__ h_all, bf16* __restrict__ c_all,
    int m, int offAbs)
{
    int idx = blockIdx.x * blockDim.x + threadIdx.x;
    if (idx >= m * HD) return;
    int i = idx / HD, j = idx - i * HD;
    int g = offAbs + i;
    int id = ids[g];
    const bf16* s = S + (size_t)i * 3840;
    const float* w = Wiou + (size_t)id * 2304;
    float iv = sigm(b2f(s[j]) + w[j] + biou[j]);
    float ov = sigm(b2f(s[HD + j]) + w[HD + j] + biou[HD + j]);
    float gv = tanhf(b2f(s[2 * HD + j]) + w[2 * HD + j] + biou[2 * HD + j]);
    float xf = Wf[(size_t)id * HD + j] + bfv[j];
    float f0 = sigm(b2f(s[3 * HD + j]) + xf);
    float f1 = sigm(b2f(s[4 * HD + j]) + xf);
    float c = iv * gv
            + f0 * b2f(c_all[(size_t)(2 * g + 1) * HD + j])
            + f1 * b2f(c_all[(size_t)(2 * g + 2) * HD + j]);
    h_all[(size_t)g * HD + j] = f2b(ov * tanhf(c));
    c_all[(size_t)g * HD + j] = f2b(c);
}

// ---------------------------------------------------------------------------
// Pass-2 cell (R8 scalar form): bf16 S(m x 4608) -> bf16 h3.
// ---------------------------------------------------------------------------
__global__ __launch_bounds__(256) void cell2_k(
    const int* __restrict__ ids, const bf16* __restrict__ S,
    const float* __restrict__ Wiou, const float* __restrict__ biou,
    const float* __restrict__ Wf, const float* __restrict__ bfv,
    const bf16* __restrict__ c_all, bf16* __restrict__ h3_all,
    int m, int g0)
{
    int idx = blockIdx.x * blockDim.x + threadIdx.x;
    if (idx >= m * HD) return;
    int i = idx / HD, j = idx - i * HD;
    int g = g0 + i;
    int id = ids[g];
    const bf16* s = S + (size_t)i * 4608;
    const float* w = Wiou + (size_t)id * 2304;
    float iv = sigm(b2f(s[j]) + w[j] + biou[j]);
    float ov = sigm(b2f(s[HD + j]) + w[HD + j] + biou[HD + j]);
    float gv = tanhf(b2f(s[2 * HD + j]) + w[2 * HD + j] + biou[2 * HD + j]);
    float xf = Wf[(size_t)id * HD + j] + bfv[j];
    float f0 = sigm(b2f(s[3 * HD + j]) + xf);
    float f1 = sigm(b2f(s[4 * HD + j]) + xf);
    float f2 = sigm(b2f(s[5 * HD + j]) + xf);
    float c = iv * gv
            + f0 * b2f(c_all[(size_t)g * HD + j])
            + f1 * b2f(c_all[(size_t)(2 * g + 1) * HD + j])
            + f2 * b2f(c_all[(size_t)(2 * g + 2) * HD + j]);
    h3_all[(size_t)g * HD + j] = f2b(ov * tanhf(c));
}

// ---------------------------------------------------------------------------
// Head softmaxes from logits L[g][128]; bc holds fused biases. fp32 out.
// ---------------------------------------------------------------------------
__global__ __launch_bounds__(256) void hsm_k(
    const float* __restrict__ L, const int* __restrict__ mask,
    const float* __restrict__ bc, float* __restrict__ out)
{
    int g = blockIdx.x * 4 + (threadIdx.x >> 6);
    if (g >= N_NODES) return;
    int t = threadIdx.x & 63;
    const float* lr = L + (size_t)g * 128;

    bool on = mask[(size_t)g * 64 + t] > 0;
    float x = (lr[4 + t] + bc[4 + t]) * (1.0f / TEMP);
    float mx = on ? x : -INFINITY;
#pragma unroll
    for (int o = 32; o; o >>= 1) mx = fmaxf(mx, __shfl_xor(mx, o));
    float e = on ? __expf(x - mx) : 0.0f;
    float s = e;
#pragma unroll
    for (int o = 32; o; o >>= 1) s += __shfl_xor(s, o);
    float r = (s > 0.f) ? e / s : (1.0f / 64.0f);
    out[(size_t)g * 68 + 4 + t] = r;

    if (t == 0) {
        float a = (lr[0] + bc[0]) * (1.0f / TEMP);
        float b = (lr[1] + bc[1]) * (1.0f / TEMP);
        float m2 = fmaxf(a, b);
        float e0 = __expf(a - m2), e1 = __expf(b - m2);
        out[(size_t)g * 68 + 0] = e0 / (e0 + e1);
        out[(size_t)g * 68 + 1] = e1 / (e0 + e1);
    } else if (t == 1) {
        float a = (lr[2] + bc[2]) * (1.0f / TEMP);
        float b = (lr[3] + bc[3]) * (1.0f / TEMP);
        float m2 = fmaxf(a, b);
        float e0 = __expf(a - m2), e1 = __expf(b - m2);
        out[(size_t)g * 68 + 2] = e0 / (e0 + e1);
        out[(size_t)g * 68 + 3] = e1 / (e0 + e1);
    }
}

// ---------------------------------------------------------------------------
extern "C" void kernel_launch(void* const* d_in, const int* in_sizes, int n_in,
                              void* d_out, int out_size, void* d_ws, size_t ws_size,
                              hipStream_t stream)
{
    const int*   ids     = (const int*)d_in[0];
    const int*   mask    = (const int*)d_in[1];
    const float* Wb_iou  = (const float*)d_in[2];
    const float* Ub_iou  = (const float*)d_in[3];
    const float* bb_iou  = (const float*)d_in[4];
    const float* Wb_f    = (const float*)d_in[5];
    const float* Ub_f    = (const float*)d_in[6];
    const float* bb_f    = (const float*)d_in[7];
    const float* Wt_iou  = (const float*)d_in[8];
    const float* Ut_iou  = (const float*)d_in[9];
    const float* bt_iou  = (const float*)d_in[10];
    const float* Wt_f    = (const float*)d_in[11];
    const float* Ut_f    = (const float*)d_in[12];
    const float* bt_f    = (const float*)d_in[13];
    const float* ffn_W1  = (const float*)d_in[14];
    const float* ffn_b1  = (const float*)d_in[15];
    const float* ffn_W2  = (const float*)d_in[16];
    const float* ffn_b2  = (const float*)d_in[17];
    const float* hl_W    = (const float*)d_in[18];
    const float* hl_b    = (const float*)d_in[19];
    const float* int_W   = (const float*)d_in[20];
    const float* int_b   = (const float*)d_in[21];
    const float* act_W   = (const float*)d_in[22];
    const float* act_b   = (const float*)d_in[23];

    // ---- workspace layout ----
    char* p = (char*)d_ws;
    bf16* h_all  = (bf16*)p; p += (size_t)NHF * 2;
    bf16* c_all  = (bf16*)p; p += (size_t)NHF * 2;
    bf16* h3_all = (bf16*)p; p += (size_t)NHF * 2;
    bf16* BT1 = (bf16*)p; p += (size_t)T1SZ * 2;
    bf16* BT2 = (bf16*)p; p += (size_t)T2SZ * 2;
    bf16* W1T = (bf16*)p; p += (size_t)WSZ * 2;
    bf16* WcT = (bf16*)p; p += (size_t)128 * 768 * 2;
    float* bc = (float*)p; p += 512;
    bf16* Sb  = (bf16*)p;              // bf16 S: up to 8191 x 4608 = 75.5 MB
    bf16* t1  = c_all;                 // FFN hidden aliases dead c
    float* Lg = (float*)h3_all;        // head logits alias h3 (dead after FFN1)

    conv_k<<<(CONVTOT + 255) / 256, 256, 0, stream>>>(
        Ub_iou, Ub_f, Ut_iou, Ut_f, ffn_W1, BT1, BT2, W1T);
    convC_k<<<128, 256, 0, stream>>>(
        ffn_W2, ffn_b2, hl_W, hl_b, int_W, int_b, act_W, act_b, WcT, bc);

    leaf_k<<<(8192 * HD + 255) / 256, 256, 0, stream>>>(
        ids, Wb_iou, bb_iou, Wt_iou, bt_iou, h_all, c_all, h3_all);

    // ---- pass 1: split mm+cell for n>=512, fused fmm for small levels ----
    for (int d = 12; d >= 0; --d) {
        int n = 1 << d;
        if (n >= 512) {
            mm_k<3, 0><<<dim3(30, n / 128), 256, 0, stream>>>(
                h_all + (size_t)(2 * n - 1) * HD, BT1, nullptr, Sb, nullptr,
                n, 3840, 1536);
            cell1_k<<<(n * HD + 255) / 256, 256, 0, stream>>>(
                ids, Sb, Wb_iou, bb_iou, Wb_f, bb_f, h_all, c_all, n, n - 1);
        } else {
            fmm_k<<<dim3(12, (n + 63) / 64), 256, 0, stream>>>(
                ids, h_all + (size_t)(2 * n - 1) * HD, BT1,
                Wb_iou, bb_iou, Wb_f, bb_f, c_all, h_all, c_all, n, n - 1);
        }
    }

    // ---- pass 2: single chunk, gather fused into GEMM ----
    mm_k<3, 1><<<dim3(36, 64), 256, 0, stream>>>(
        h_all, BT2, nullptr, Sb, nullptr, NLEAF_OFF, 4608, 2304);
    cell2_k<<<(NLEAF_OFF * HD + 255) / 256, 256, 0, stream>>>(
        ids, Sb, Wt_iou, bt_iou, Wt_f, bt_f, c_all, h3_all, NLEAF_OFF, 0);

    // ---- FFN1 (relu epilogue) ----
    mm_k<1, 0><<<dim3(6, 128), 256, 0, stream>>>(
        h3_all, W1T, nullptr, t1, ffn_b1, N_NODES, 768, 768);

    // ---- heads: folded logits GEMM (t1 @ WcT, FFN2 absorbed) + softmax ----
    mm_k<0, 0><<<dim3(1, 128), 256, 0, stream>>>(
        t1, WcT, Lg, nullptr, nullptr, N_NODES, 128, 768);
    hsm_k<<<(N_NODES + 3) / 4, 256, 0, stream>>>(
        Lg, mask, bc, (float*)d_out);
}

// Round 12
// 1094.849 us; speedup vs baseline: 1.2346x; 1.0428x over previous
//
#include <hip/hip_runtime.h>
#include <hip/hip_bf16.h>

#define HD 768
#define N_NODES 16383
#define NLEAF_OFF 8191     // first leaf node index (level d=13 offset)
#define NHF 12582144       // N_NODES * HD
#define TEMP 3.0f

using bf16 = __hip_bfloat16;
typedef __attribute__((ext_vector_type(8))) short bf16x8;
typedef __attribute__((ext_vector_type(4))) float f32x4;

__device__ __forceinline__ float sigm(float x) { return 1.0f / (1.0f + __expf(-x)); }
__device__ __forceinline__ float b2f(bf16 v)   { return __bfloat162float(v); }
__device__ __forceinline__ bf16  f2b(float v)  { return __float2bfloat16(v); }

// async global->LDS, 16B per lane. LDS dest = wave-uniform base + lane*16.
__device__ __forceinline__ void gload16(const void* g, void* l) {
    __builtin_amdgcn_global_load_lds(
        (const __attribute__((address_space(1))) unsigned int*)g,
        (__attribute__((address_space(3))) unsigned int*)l, 16, 0, 0);
}

#define T1SZ 5898240      // 3840*1536
#define T2SZ 10616832     // 4608*2304
#define WSZ  589824       // 768*768

// ---------------------------------------------------------------------------
// Tiled transpose-convert: builds BT1, BT2, W1T (bf16, gate-major B^T) with
// coalesced reads AND writes. 16 pieces on a 1-D grid; 32x32 tiles via LDS.
// Piece tile ranges:
//  [0,3456)      BT1 iou : src Ub_iou (1536k x 2304n), dst BT1, S=1536
//  [3456,5760)   BT1 f   : 4 pieces (kk,l), src 768x768, dst offset, S=1536
//  [5760,10944)  BT2 iou : src Ut_iou (2304 x 2304), dst BT2, S=2304
//  [10944,16128) BT2 f   : 9 pieces (kk,l), src 768x768, dst offset, S=2304
//  [16128,16704) W1T     : src ffn_W1 (768 x 768), dst W1T, S=768
// ---------------------------------------------------------------------------
__global__ __launch_bounds__(256) void tconv_k(
    const float* __restrict__ Ub_iou, const float* __restrict__ Ub_f,
    const float* __restrict__ Ut_iou, const float* __restrict__ Ut_f,
    const float* __restrict__ ffn_W1,
    bf16* __restrict__ BT1, bf16* __restrict__ BT2, bf16* __restrict__ W1T)
{
    int t = blockIdx.x;
    const float* src; bf16* dst; int C, S, kt, nt;
    if (t < 3456) {
        src = Ub_iou; dst = BT1; C = 2304; S = 1536;
        kt = t % 48; nt = t / 48;
    } else if (t < 5760) {
        int u = t - 3456; int piece = u / 576; u -= piece * 576;
        int kk = piece >> 1, l = piece & 1;
        src = Ub_f + (size_t)(kk * 2 + l) * WSZ;
        dst = BT1 + (size_t)(2304 + kk * 768) * 1536 + l * 768;
        C = 768; S = 1536; kt = u % 24; nt = u / 24;
    } else if (t < 10944) {
        int u = t - 5760;
        src = Ut_iou; dst = BT2; C = 2304; S = 2304;
        kt = u % 72; nt = u / 72;
    } else if (t < 16128) {
        int u = t - 10944; int piece = u / 576; u -= piece * 576;
        int kk = piece / 3, l = piece - kk * 3;
        src = Ut_f + (size_t)(kk * 3 + l) * WSZ;
        dst = BT2 + (size_t)(2304 + kk * 768) * 2304 + l * 768;
        C = 768; S = 2304; kt = u % 24; nt = u / 24;
    } else {
        int u = t - 16128;
        src = ffn_W1; dst = W1T; C = 768; S = 768;
        kt = u % 24; nt = u / 24;
    }
    int k0 = kt * 32, n0 = nt * 32;

    __shared__ float tl[32][33];
    int rr = threadIdx.x >> 5, c = threadIdx.x & 31;
#pragma unroll
    for (int r = 0; r < 32; r += 8)
        tl[rr + r][c] = src[(size_t)(k0 + rr + r) * C + n0 + c];
    __syncthreads();
#pragma unroll
    for (int r = 0; r < 32; r += 8)
        dst[(size_t)(n0 + rr + r) * S + k0 + c] = f2b(tl[c][rr + r]);
}

// ---------------------------------------------------------------------------
// Misc converts: WhT[128][768] (head weights, zero-padded) + W2 -> bf16 cast.
// ---------------------------------------------------------------------------
#define HSZ2 98304        // 128*768
__global__ __launch_bounds__(256) void misc_k(
    const float* __restrict__ hlW, const float* __restrict__ intW,
    const float* __restrict__ actW, const float* __restrict__ W2,
    bf16* __restrict__ WhT, bf16* __restrict__ W2b)
{
    int idx = blockIdx.x * 256 + threadIdx.x;
    if (idx < HSZ2) {
        int n = idx / 768, j = idx - n * 768;
        float v = 0.f;
        if (n < 2)       v = hlW[(size_t)j * 2 + n];
        else if (n < 4)  v = intW[(size_t)j * 2 + (n - 2)];
        else if (n < 68) v = actW[(size_t)j * 64 + (n - 4)];
        WhT[idx] = f2b(v);
    } else if (idx < HSZ2 + WSZ) {
        int i2 = idx - HSZ2;
        W2b[i2] = f2b(W2[i2]);
    }
}

// Fused bias: bc[n] = sum_j b2[j]*Wh[j][n] + head_bias(n). One block, 128 thr.
__global__ __launch_bounds__(128) void bck_k(
    const float* __restrict__ b2,
    const float* __restrict__ hlW, const float* __restrict__ hlb,
    const float* __restrict__ intW, const float* __restrict__ intb,
    const float* __restrict__ actW, const float* __restrict__ actb,
    float* __restrict__ bc)
{
    int n = threadIdx.x;
    float s = 0.f;
    for (int j = 0; j < 768; ++j) {
        float wh = 0.f;
        if (n < 2)       wh = hlW[(size_t)j * 2 + n];
        else if (n < 4)  wh = intW[(size_t)j * 2 + (n - 2)];
        else if (n < 68) wh = actW[(size_t)j * 64 + (n - 4)];
        s = fmaf(b2[j], wh, s);
    }
    float hb = 0.f;
    if (n < 2)       hb = hlb[n];
    else if (n < 4)  hb = intb[n - 2];
    else if (n < 68) hb = actb[n - 4];
    bc[n] = s + hb;
}

// ---------------------------------------------------------------------------
// Fused leaf kernel (R8 scalar form): pass-1 h,c AND pass-2 h3.
// ---------------------------------------------------------------------------
__global__ __launch_bounds__(256) void leaf_k(
    const int* __restrict__ ids,
    const float* __restrict__ Wb, const float* __restrict__ bb,
    const float* __restrict__ Wt, const float* __restrict__ bt,
    bf16* __restrict__ h_all, bf16* __restrict__ c_all, bf16* __restrict__ h3_all)
{
    int idx = blockIdx.x * blockDim.x + threadIdx.x;
    if (idx >= 8192 * HD) return;
    int i = idx / HD, j = idx - i * HD;
    int g = NLEAF_OFF + i;
    int id = ids[g];
    const float* w = Wb + (size_t)id * 3 * HD;
    float iv = sigm(w[j] + bb[j]);
    float ov = sigm(w[HD + j] + bb[HD + j]);
    float gv = tanhf(w[2 * HD + j] + bb[2 * HD + j]);
    float c = iv * gv;
    h_all[(size_t)g * HD + j] = f2b(ov * tanhf(c));
    c_all[(size_t)g * HD + j] = f2b(c);

    const float* w2 = Wt + (size_t)id * 3 * HD;
    float iv2 = sigm(w2[j] + bt[j]);
    float ov2 = sigm(w2[HD + j] + bt[HD + j]);
    float gv2 = tanhf(w2[2 * HD + j] + bt[2 * HD + j]);
    float c2 = iv2 * gv2;
    h3_all[(size_t)g * HD + j] = f2b(ov2 * tanhf(c2));
}

// ---------------------------------------------------------------------------
// bf16 MFMA GEMM (R8-proven m97 structure): C[M x N] = A @ BT^T.
// 128x128 tile, 4 waves, BK=32, linear LDS [128][32], global_load_lds staging.
// GATHER=1 (pass 2): A row r = [h(r), h(2r+1), h(2r+2)] via per-lane sources.
// EPI 0: fp32 Cf. EPI 1: bias+relu bf16. EPI 3: plain bf16.
// ---------------------------------------------------------------------------
template <int EPI, int GATHER>
__global__ __launch_bounds__(256) void mm_k(
    const bf16* __restrict__ A, const bf16* __restrict__ BT,
    float* __restrict__ Cf, bf16* __restrict__ Cb,
    const float* __restrict__ bias,
    int M, int N, int K)
{
    __shared__ short As[128 * 32];
    __shared__ short Bs[128 * 32];

    int tid  = threadIdx.x;
    int lane = tid & 63;
    int wave = tid >> 6;
    int wr = wave >> 1, wc = wave & 1;
    int bx = blockIdx.x, by = blockIdx.y;

    f32x4 acc[4][4] = {};

    int sr  = lane >> 2;
    int sc8 = (lane & 3) * 8;
    int arow0 = by * 128 + wave * 16 + sr;
    int arow1 = arow0 + 64;
    if (arow0 > M - 1) arow0 = M - 1;
    if (arow1 > M - 1) arow1 = M - 1;
    const bf16* gA0 = A + (size_t)arow0 * K + sc8;
    const bf16* gA1 = A + (size_t)arow1 * K + sc8;
    const bf16* gB0 = BT + (size_t)(bx * 128 + wave * 16 + sr) * K + sc8;
    const bf16* gB1 = BT + (size_t)(bx * 128 + wave * 16 + sr + 64) * K + sc8;
    short* lA0 = As + wave * 512;
    short* lA1 = As + wave * 512 + 2048;
    short* lB0 = Bs + wave * 512;
    short* lB1 = Bs + wave * 512 + 2048;

    int fr = lane & 15;
    int fk = (lane >> 4) << 3;
    const short* pAf = As + (wr * 64 + fr) * 32 + fk;
    const short* pBf = Bs + (wc * 64 + fr) * 32 + fk;

    for (int kt = 0; kt < K; kt += 32) {
        if constexpr (GATHER) {
            int ch = (kt >= 768) + (kt >= 1536);
            int col = kt - ch * 768 + sc8;
            int n0 = (ch == 0) ? arow0 : (2 * arow0 + ch);
            int n1 = (ch == 0) ? arow1 : (2 * arow1 + ch);
            gload16(A + (size_t)n0 * HD + col, lA0);
            gload16(A + (size_t)n1 * HD + col, lA1);
        } else {
            gload16(gA0 + kt, lA0);
            gload16(gA1 + kt, lA1);
        }
        gload16(gB0 + kt, lB0);
        gload16(gB1 + kt, lB1);
        __syncthreads();

        bf16x8 a[4], b[4];
#pragma unroll
        for (int m = 0; m < 4; m++) a[m] = *(const bf16x8*)(pAf + m * 512);
#pragma unroll
        for (int n = 0; n < 4; n++) b[n] = *(const bf16x8*)(pBf + n * 512);
#pragma unroll
        for (int m = 0; m < 4; m++)
#pragma unroll
            for (int n = 0; n < 4; n++)
                acc[m][n] = __builtin_amdgcn_mfma_f32_16x16x32_bf16(
                    a[m], b[n], acc[m][n], 0, 0, 0);
        __syncthreads();
    }

    int rbase = by * 128 + wr * 64 + ((lane >> 4) << 2);
    int cbase = bx * 128 + wc * 64 + fr;
#pragma unroll
    for (int m = 0; m < 4; m++) {
#pragma unroll
        for (int r = 0; r < 4; r++) {
            int row = rbase + m * 16 + r;
            if (row >= M) continue;
#pragma unroll
            for (int n = 0; n < 4; n++) {
                int col = cbase + n * 16;
                float v = acc[m][n][r];
                if constexpr (EPI == 1) {
                    v = fmaxf(v + bias[col], 0.f);
                    Cb[(size_t)row * N + col] = f2b(v);
                } else if constexpr (EPI == 3) {
                    Cb[(size_t)row * N + col] = f2b(v);
                } else {
                    Cf[(size_t)row * N + col] = v;
                }
            }
        }
    }
}

// ---------------------------------------------------------------------------
// FUSED small-level kernel (pass 1, n < 512). 64x64x5-gate tile, BK=32.
// ---------------------------------------------------------------------------
__global__ __launch_bounds__(256) void fmm_k(
    const int* __restrict__ ids,
    const bf16* __restrict__ Abase,
    const bf16* __restrict__ BT,
    const float* __restrict__ Wiou, const float* __restrict__ biou,
    const float* __restrict__ Wf, const float* __restrict__ bfv,
    const bf16* __restrict__ c_all,
    bf16* __restrict__ h_out, bf16* __restrict__ c_out,
    int M, int off)
{
    constexpr int NG = 5;
    constexpr int K  = 1536;
    __shared__ short As[64 * 32];
    __shared__ short Bs[NG * 64 * 32];

    int tid  = threadIdx.x;
    int lane = tid & 63;
    int wave = tid >> 6;
    int wr = wave >> 1, wc = wave & 1;
    int bx = blockIdx.x, by = blockIdx.y;

    f32x4 acc[NG][2][2] = {};

    int sr  = lane >> 2;
    int sc8 = (lane & 3) * 8;
    int arow = by * 64 + wave * 16 + sr;
    if (arow > M - 1) arow = M - 1;

    const bf16* gB[NG];
    short* lB[NG];
#pragma unroll
    for (int t = 0; t < NG; ++t) {
        int s = wave + 4 * t;
        int gb = s >> 2, q = s & 3;
        gB[t] = BT + (size_t)(gb * 768 + bx * 64 + q * 16 + sr) * K + sc8;
        lB[t] = Bs + gb * 2048 + q * 512;
    }
    short* lA = As + wave * 512;
    const bf16* gA1 = Abase + (size_t)arow * 1536 + sc8;

    int fr = lane & 15;
    int fk = (lane >> 4) << 3;
    const short* pA = As + (wr * 32 + fr) * 32 + fk;
    const short* pB = Bs + (wc * 32 + fr) * 32 + fk;

    for (int kt = 0; kt < K; kt += 32) {
        gload16(gA1 + kt, lA);
#pragma unroll
        for (int t = 0; t < NG; ++t) gload16(gB[t] + kt, lB[t]);
        __syncthreads();

        bf16x8 a0 = *(const bf16x8*)pA;
        bf16x8 a1 = *(const bf16x8*)(pA + 512);
#pragma unroll
        for (int g = 0; g < NG; ++g) {
            bf16x8 b0 = *(const bf16x8*)(pB + g * 2048);
            bf16x8 b1 = *(const bf16x8*)(pB + g * 2048 + 512);
            acc[g][0][0] = __builtin_amdgcn_mfma_f32_16x16x32_bf16(a0, b0, acc[g][0][0], 0, 0, 0);
            acc[g][0][1] = __builtin_amdgcn_mfma_f32_16x16x32_bf16(a0, b1, acc[g][0][1], 0, 0, 0);
            acc[g][1][0] = __builtin_amdgcn_mfma_f32_16x16x32_bf16(a1, b0, acc[g][1][0], 0, 0, 0);
            acc[g][1][1] = __builtin_amdgcn_mfma_f32_16x16x32_bf16(a1, b1, acc[g][1][1], 0, 0, 0);
        }
        __syncthreads();
    }

    int lr4 = (lane >> 4) << 2;
    int c0  = bx * 64 + wc * 32 + fr;
#pragma unroll
    for (int m = 0; m < 2; ++m) {
#pragma unroll
        for (int r = 0; r < 4; ++r) {
            int row = by * 64 + wr * 32 + m * 16 + lr4 + r;
            if (row >= M) continue;
            int g = off + row;
            int id = ids[g];
            const float* wi = Wiou + (size_t)id * 2304;
            const float* wf = Wf + (size_t)id * 768;
#pragma unroll
            for (int n = 0; n < 2; ++n) {
                int j = c0 + n * 16;
                float iv = sigm(acc[0][m][n][r] + wi[j] + biou[j]);
                float ov = sigm(acc[1][m][n][r] + wi[768 + j] + biou[768 + j]);
                float uv = tanhf(acc[2][m][n][r] + wi[1536 + j] + biou[1536 + j]);
                float xf = wf[j] + bfv[j];
                float f0 = sigm(acc[3][m][n][r] + xf);
                float f1 = sigm(acc[4][m][n][r] + xf);
                float cv = iv * uv
                         + f0 * b2f(c_all[(size_t)(2 * g + 1) * HD + j])
                         + f1 * b2f(c_all[(size_t)(2 * g + 2) * HD + j]);
                c_out[(size_t)g * HD + j] = f2b(cv);
                h_out[(size_t)g * HD + j] = f2b(ov * tanhf(cv));
            }
        }
    }
}

// ---------------------------------------------------------------------------
// Pass-1 cell (R8 scalar form): bf16 S(m x 3840) -> bf16 h,c.
// ---------------------------------------------------------------------------
__global__ __launch_bounds__(256) void cell1_k(
    const int* __restrict__ ids, const bf16* __restrict__ S,
    const float* __restrict__ Wiou, const float* __restrict__ biou,
    const float* __restrict__ Wf, const float* __restrict__ bfv,
    bf16* __restrict__ h_all, bf16* __restrict__ c_all,
    int m, int offAbs)
{
    int idx = blockIdx.x * blockDim.x + threadIdx.x;
    if (idx >= m * HD) return;
    int i = idx / HD, j = idx - i * HD;
    int g = offAbs + i;
    int id = ids[g];
    const bf16* s = S + (size_t)i * 3840;
    const float* w = Wiou + (size_t)id * 2304;
    float iv = sigm(b2f(s[j]) + w[j] + biou[j]);
    float ov = sigm(b2f(s[HD + j]) + w[HD + j] + biou[HD + j]);
    float gv = tanhf(b2f(s[2 * HD + j]) + w[2 * HD + j] + biou[2 * HD + j]);
    float xf = Wf[(size_t)id * HD + j] + bfv[j];
    float f0 = sigm(b2f(s[3 * HD + j]) + xf);
    float f1 = sigm(b2f(s[4 * HD + j]) + xf);
    float c = iv * gv
            + f0 * b2f(c_all[(size_t)(2 * g + 1) * HD + j])
            + f1 * b2f(c_all[(size_t)(2 * g + 2) * HD + j]);
    h_all[(size_t)g * HD + j] = f2b(ov * tanhf(c));
    c_all[(size_t)g * HD + j] = f2b(c);
}

// ---------------------------------------------------------------------------
// Pass-2 cell (R8 scalar form): bf16 S(m x 4608) -> bf16 h3.
// ---------------------------------------------------------------------------
__global__ __launch_bounds__(256) void cell2_k(
    const int* __restrict__ ids, const bf16* __restrict__ S,
    const float* __restrict__ Wiou, const float* __restrict__ biou,
    const float* __restrict__ Wf, const float* __restrict__ bfv,
    const bf16* __restrict__ c_all, bf16* __restrict__ h3_all,
    int m, int g0)
{
    int idx = blockIdx.x * blockDim.x + threadIdx.x;
    if (idx >= m * HD) return;
    int i = idx / HD, j = idx - i * HD;
    int g = g0 + i;
    int id = ids[g];
    const bf16* s = S + (size_t)i * 4608;
    const float* w = Wiou + (size_t)id * 2304;
    float iv = sigm(b2f(s[j]) + w[j] + biou[j]);
    float ov = sigm(b2f(s[HD + j]) + w[HD + j] + biou[HD + j]);
    float gv = tanhf(b2f(s[2 * HD + j]) + w[2 * HD + j] + biou[2 * HD + j]);
    float xf = Wf[(size_t)id * HD + j] + bfv[j];
    float f0 = sigm(b2f(s[3 * HD + j]) + xf);
    float f1 = sigm(b2f(s[4 * HD + j]) + xf);
    float f2 = sigm(b2f(s[5 * HD + j]) + xf);
    float c = iv * gv
            + f0 * b2f(c_all[(size_t)g * HD + j])
            + f1 * b2f(c_all[(size_t)(2 * g + 1) * HD + j])
            + f2 * b2f(c_all[(size_t)(2 * g + 2) * HD + j]);
    h3_all[(size_t)g * HD + j] = f2b(ov * tanhf(c));
}

// ---------------------------------------------------------------------------
// Head softmaxes from logits L[g][128]; bc holds fused biases. fp32 out.
// ---------------------------------------------------------------------------
__global__ __launch_bounds__(256) void hsm_k(
    const float* __restrict__ L, const int* __restrict__ mask,
    const float* __restrict__ bc, float* __restrict__ out)
{
    int g = blockIdx.x * 4 + (threadIdx.x >> 6);
    if (g >= N_NODES) return;
    int t = threadIdx.x & 63;
    const float* lr = L + (size_t)g * 128;

    bool on = mask[(size_t)g * 64 + t] > 0;
    float x = (lr[4 + t] + bc[4 + t]) * (1.0f / TEMP);
    float mx = on ? x : -INFINITY;
#pragma unroll
    for (int o = 32; o; o >>= 1) mx = fmaxf(mx, __shfl_xor(mx, o));
    float e = on ? __expf(x - mx) : 0.0f;
    float s = e;
#pragma unroll
    for (int o = 32; o; o >>= 1) s += __shfl_xor(s, o);
    float r = (s > 0.f) ? e / s : (1.0f / 64.0f);
    out[(size_t)g * 68 + 4 + t] = r;

    if (t == 0) {
        float a = (lr[0] + bc[0]) * (1.0f / TEMP);
        float b = (lr[1] + bc[1]) * (1.0f / TEMP);
        float m2 = fmaxf(a, b);
        float e0 = __expf(a - m2), e1 = __expf(b - m2);
        out[(size_t)g * 68 + 0] = e0 / (e0 + e1);
        out[(size_t)g * 68 + 1] = e1 / (e0 + e1);
    } else if (t == 1) {
        float a = (lr[2] + bc[2]) * (1.0f / TEMP);
        float b = (lr[3] + bc[3]) * (1.0f / TEMP);
        float m2 = fmaxf(a, b);
        float e0 = __expf(a - m2), e1 = __expf(b - m2);
        out[(size_t)g * 68 + 2] = e0 / (e0 + e1);
        out[(size_t)g * 68 + 3] = e1 / (e0 + e1);
    }
}

// ---------------------------------------------------------------------------
extern "C" void kernel_launch(void* const* d_in, const int* in_sizes, int n_in,
                              void* d_out, int out_size, void* d_ws, size_t ws_size,
                              hipStream_t stream)
{
    const int*   ids     = (const int*)d_in[0];
    const int*   mask    = (const int*)d_in[1];
    const float* Wb_iou  = (const float*)d_in[2];
    const float* Ub_iou  = (const float*)d_in[3];
    const float* bb_iou  = (const float*)d_in[4];
    const float* Wb_f    = (const float*)d_in[5];
    const float* Ub_f    = (const float*)d_in[6];
    const float* bb_f    = (const float*)d_in[7];
    const float* Wt_iou  = (const float*)d_in[8];
    const float* Ut_iou  = (const float*)d_in[9];
    const float* bt_iou  = (const float*)d_in[10];
    const float* Wt_f    = (const float*)d_in[11];
    const float* Ut_f    = (const float*)d_in[12];
    const float* bt_f    = (const float*)d_in[13];
    const float* ffn_W1  = (const float*)d_in[14];
    const float* ffn_b1  = (const float*)d_in[15];
    const float* ffn_W2  = (const float*)d_in[16];
    const float* ffn_b2  = (const float*)d_in[17];
    const float* hl_W    = (const float*)d_in[18];
    const float* hl_b    = (const float*)d_in[19];
    const float* int_W   = (const float*)d_in[20];
    const float* int_b   = (const float*)d_in[21];
    const float* act_W   = (const float*)d_in[22];
    const float* act_b   = (const float*)d_in[23];

    // ---- workspace layout ----
    char* p = (char*)d_ws;
    bf16* h_all  = (bf16*)p; p += (size_t)NHF * 2;
    bf16* c_all  = (bf16*)p; p += (size_t)NHF * 2;
    bf16* h3_all = (bf16*)p; p += (size_t)NHF * 2;
    bf16* BT1 = (bf16*)p; p += (size_t)T1SZ * 2;
    bf16* BT2 = (bf16*)p; p += (size_t)T2SZ * 2;
    bf16* W1T = (bf16*)p; p += (size_t)WSZ * 2;
    bf16* WcT = (bf16*)p; p += (size_t)128 * 768 * 2;
    bf16* WhT = (bf16*)p; p += (size_t)HSZ2 * 2;
    bf16* W2b = (bf16*)p; p += (size_t)WSZ * 2;
    float* bc = (float*)p; p += 512;
    bf16* Sb  = (bf16*)p;              // bf16 S: up to 8191 x 4608 = 75.5 MB
    bf16* t1  = c_all;                 // FFN hidden aliases dead c
    float* Lg = (float*)h3_all;        // head logits alias h3 (dead after FFN1)

    // ---- weight conversions (coalesced) ----
    tconv_k<<<16704, 256, 0, stream>>>(
        Ub_iou, Ub_f, Ut_iou, Ut_f, ffn_W1, BT1, BT2, W1T);
    misc_k<<<(HSZ2 + WSZ + 255) / 256, 256, 0, stream>>>(
        hl_W, int_W, act_W, ffn_W2, WhT, W2b);
    bck_k<<<1, 128, 0, stream>>>(
        ffn_b2, hl_W, hl_b, int_W, int_b, act_W, act_b, bc);
    // WcT[n][k] = sum_j WhT[n][j] * W2[k][j]  (MFMA fold of FFN2 into heads)
    mm_k<3, 0><<<dim3(6, 1), 256, 0, stream>>>(
        WhT, W2b, nullptr, WcT, nullptr, 128, 768, 768);

    leaf_k<<<(8192 * HD + 255) / 256, 256, 0, stream>>>(
        ids, Wb_iou, bb_iou, Wt_iou, bt_iou, h_all, c_all, h3_all);

    // ---- pass 1: split mm+cell for n>=512, fused fmm for small levels ----
    for (int d = 12; d >= 0; --d) {
        int n = 1 << d;
        if (n >= 512) {
            mm_k<3, 0><<<dim3(30, n / 128), 256, 0, stream>>>(
                h_all + (size_t)(2 * n - 1) * HD, BT1, nullptr, Sb, nullptr,
                n, 3840, 1536);
            cell1_k<<<(n * HD + 255) / 256, 256, 0, stream>>>(
                ids, Sb, Wb_iou, bb_iou, Wb_f, bb_f, h_all, c_all, n, n - 1);
        } else {
            fmm_k<<<dim3(12, (n + 63) / 64), 256, 0, stream>>>(
                ids, h_all + (size_t)(2 * n - 1) * HD, BT1,
                Wb_iou, bb_iou, Wb_f, bb_f, c_all, h_all, c_all, n, n - 1);
        }
    }

    // ---- pass 2: single chunk, gather fused into GEMM ----
    mm_k<3, 1><<<dim3(36, 64), 256, 0, stream>>>(
        h_all, BT2, nullptr, Sb, nullptr, NLEAF_OFF, 4608, 2304);
    cell2_k<<<(NLEAF_OFF * HD + 255) / 256, 256, 0, stream>>>(
        ids, Sb, Wt_iou, bt_iou, Wt_f, bt_f, c_all, h3_all, NLEAF_OFF, 0);

    // ---- FFN1 (relu epilogue) ----
    mm_k<1, 0><<<dim3(6, 128), 256, 0, stream>>>(
        h3_all, W1T, nullptr, t1, ffn_b1, N_NODES, 768, 768);

    // ---- heads: folded logits GEMM (t1 @ WcT, FFN2 absorbed) + softmax ----
    mm_k<0, 0><<<dim3(1, 128), 256, 0, stream>>>(
        t1, WcT, Lg, nullptr, nullptr, N_NODES, 128, 768);
    hsm_k<<<(N_NODES + 3) / 4, 256, 0, stream>>>(
        Lg, mask, bc, (float*)d_out);
}

// Round 13
// 841.959 us; speedup vs baseline: 1.6055x; 1.3004x over previous
//
#include <hip/hip_runtime.h>
#include <hip/hip_bf16.h>

#define HD 768
#define N_NODES 16383
#define NLEAF_OFF 8191     // first leaf node index (level d=13 offset)
#define NHF 12582144       // N_NODES * HD
#define TEMP 3.0f

using bf16 = __hip_bfloat16;
typedef __attribute__((ext_vector_type(8))) short bf16x8;
typedef __attribute__((ext_vector_type(4))) float f32x4;

__device__ __forceinline__ float sigm(float x) { return 1.0f / (1.0f + __expf(-x)); }
__device__ __forceinline__ float b2f(bf16 v)   { return __bfloat162float(v); }
__device__ __forceinline__ bf16  f2b(float v)  { return __float2bfloat16(v); }

// async global->LDS, 16B per lane. LDS dest = wave-uniform base + lane*16.
__device__ __forceinline__ void gload16(const void* g, void* l) {
    __builtin_amdgcn_global_load_lds(
        (const __attribute__((address_space(1))) unsigned int*)g,
        (__attribute__((address_space(3))) unsigned int*)l, 16, 0, 0);
}

#define T1SZ 5898240      // 3840*1536
#define T2SZ 10616832     // 4608*2304
#define WSZ  589824       // 768*768

// ---------------------------------------------------------------------------
// Tiled transpose-convert: builds BT1, BT2, W1T (bf16, gate-major B^T) with
// coalesced reads AND writes. 32x32 tiles via LDS; 1-D piece table.
// ---------------------------------------------------------------------------
__global__ __launch_bounds__(256) void tconv_k(
    const float* __restrict__ Ub_iou, const float* __restrict__ Ub_f,
    const float* __restrict__ Ut_iou, const float* __restrict__ Ut_f,
    const float* __restrict__ ffn_W1,
    bf16* __restrict__ BT1, bf16* __restrict__ BT2, bf16* __restrict__ W1T)
{
    int t = blockIdx.x;
    const float* src; bf16* dst; int C, S, kt, nt;
    if (t < 3456) {
        src = Ub_iou; dst = BT1; C = 2304; S = 1536;
        kt = t % 48; nt = t / 48;
    } else if (t < 5760) {
        int u = t - 3456; int piece = u / 576; u -= piece * 576;
        int kk = piece >> 1, l = piece & 1;
        src = Ub_f + (size_t)(kk * 2 + l) * WSZ;
        dst = BT1 + (size_t)(2304 + kk * 768) * 1536 + l * 768;
        C = 768; S = 1536; kt = u % 24; nt = u / 24;
    } else if (t < 10944) {
        int u = t - 5760;
        src = Ut_iou; dst = BT2; C = 2304; S = 2304;
        kt = u % 72; nt = u / 72;
    } else if (t < 16128) {
        int u = t - 10944; int piece = u / 576; u -= piece * 576;
        int kk = piece / 3, l = piece - kk * 3;
        src = Ut_f + (size_t)(kk * 3 + l) * WSZ;
        dst = BT2 + (size_t)(2304 + kk * 768) * 2304 + l * 768;
        C = 768; S = 2304; kt = u % 24; nt = u / 24;
    } else {
        int u = t - 16128;
        src = ffn_W1; dst = W1T; C = 768; S = 768;
        kt = u % 24; nt = u / 24;
    }
    int k0 = kt * 32, n0 = nt * 32;

    __shared__ float tl[32][33];
    int rr = threadIdx.x >> 5, c = threadIdx.x & 31;
#pragma unroll
    for (int r = 0; r < 32; r += 8)
        tl[rr + r][c] = src[(size_t)(k0 + rr + r) * C + n0 + c];
    __syncthreads();
#pragma unroll
    for (int r = 0; r < 32; r += 8)
        dst[(size_t)(n0 + rr + r) * S + k0 + c] = f2b(tl[c][rr + r]);
}

// ---------------------------------------------------------------------------
// Misc converts: WhT[128][768] (head weights, zero-padded) + W2 -> bf16 cast.
// ---------------------------------------------------------------------------
#define HSZ2 98304        // 128*768
__global__ __launch_bounds__(256) void misc_k(
    const float* __restrict__ hlW, const float* __restrict__ intW,
    const float* __restrict__ actW, const float* __restrict__ W2,
    bf16* __restrict__ WhT, bf16* __restrict__ W2b)
{
    int idx = blockIdx.x * 256 + threadIdx.x;
    if (idx < HSZ2) {
        int n = idx / 768, j = idx - n * 768;
        float v = 0.f;
        if (n < 2)       v = hlW[(size_t)j * 2 + n];
        else if (n < 4)  v = intW[(size_t)j * 2 + (n - 2)];
        else if (n < 68) v = actW[(size_t)j * 64 + (n - 4)];
        WhT[idx] = f2b(v);
    } else if (idx < HSZ2 + WSZ) {
        int i2 = idx - HSZ2;
        W2b[i2] = f2b(W2[i2]);
    }
}

// Fused bias: bc[n] = sum_j b2[j]*Wh[j][n] + head_bias(n). One block, 128 thr.
__global__ __launch_bounds__(128) void bck_k(
    const float* __restrict__ b2,
    const float* __restrict__ hlW, const float* __restrict__ hlb,
    const float* __restrict__ intW, const float* __restrict__ intb,
    const float* __restrict__ actW, const float* __restrict__ actb,
    float* __restrict__ bc)
{
    int n = threadIdx.x;
    float s = 0.f;
    for (int j = 0; j < 768; ++j) {
        float wh = 0.f;
        if (n < 2)       wh = hlW[(size_t)j * 2 + n];
        else if (n < 4)  wh = intW[(size_t)j * 2 + (n - 2)];
        else if (n < 68) wh = actW[(size_t)j * 64 + (n - 4)];
        s = fmaf(b2[j], wh, s);
    }
    float hb = 0.f;
    if (n < 2)       hb = hlb[n];
    else if (n < 4)  hb = intb[n - 2];
    else if (n < 68) hb = actb[n - 4];
    bc[n] = s + hb;
}

// ---------------------------------------------------------------------------
// Fused leaf kernel (R8 scalar form): pass-1 h,c AND pass-2 h3.
// ---------------------------------------------------------------------------
__global__ __launch_bounds__(256) void leaf_k(
    const int* __restrict__ ids,
    const float* __restrict__ Wb, const float* __restrict__ bb,
    const float* __restrict__ Wt, const float* __restrict__ bt,
    bf16* __restrict__ h_all, bf16* __restrict__ c_all, bf16* __restrict__ h3_all)
{
    int idx = blockIdx.x * blockDim.x + threadIdx.x;
    if (idx >= 8192 * HD) return;
    int i = idx / HD, j = idx - i * HD;
    int g = NLEAF_OFF + i;
    int id = ids[g];
    const float* w = Wb + (size_t)id * 3 * HD;
    float iv = sigm(w[j] + bb[j]);
    float ov = sigm(w[HD + j] + bb[HD + j]);
    float gv = tanhf(w[2 * HD + j] + bb[2 * HD + j]);
    float c = iv * gv;
    h_all[(size_t)g * HD + j] = f2b(ov * tanhf(c));
    c_all[(size_t)g * HD + j] = f2b(c);

    const float* w2 = Wt + (size_t)id * 3 * HD;
    float iv2 = sigm(w2[j] + bt[j]);
    float ov2 = sigm(w2[HD + j] + bt[HD + j]);
    float gv2 = tanhf(w2[2 * HD + j] + bt[2 * HD + j]);
    float c2 = iv2 * gv2;
    h3_all[(size_t)g * HD + j] = f2b(ov2 * tanhf(c2));
}

// ---------------------------------------------------------------------------
// bf16 MFMA GEMM (R8-proven m97 structure), now with K-split support.
// C[M x N] = A[:, z*Kc:(z+1)*Kc] @ BT[:, same]^T for z = blockIdx.z.
// EPI==0 writes fp32 partial at Cf + z*M*N. KS=1 (gridDim.z=1) == old kernel.
// 128x128 tile, 4 waves, BK=32, linear LDS, global_load_lds staging.
// GATHER=1 (pass 2): A row r = [h(r), h(2r+1), h(2r+2)] via per-lane sources.
// EPI 0: fp32 Cf. EPI 1: bias+relu bf16. EPI 3: plain bf16.
// ---------------------------------------------------------------------------
template <int EPI, int GATHER>
__global__ __launch_bounds__(256) void mm_k(
    const bf16* __restrict__ A, const bf16* __restrict__ BT,
    float* __restrict__ Cf, bf16* __restrict__ Cb,
    const float* __restrict__ bias,
    int M, int N, int Kc, int Kfull)
{
    __shared__ short As[128 * 32];
    __shared__ short Bs[128 * 32];

    int tid  = threadIdx.x;
    int lane = tid & 63;
    int wave = tid >> 6;
    int wr = wave >> 1, wc = wave & 1;
    int bx = blockIdx.x, by = blockIdx.y;
    int colbase = blockIdx.z * Kc;
    if constexpr (EPI == 0) Cf += (size_t)blockIdx.z * ((size_t)M * N);

    f32x4 acc[4][4] = {};

    int sr  = lane >> 2;
    int sc8 = (lane & 3) * 8;
    int arow0 = by * 128 + wave * 16 + sr;
    int arow1 = arow0 + 64;
    if (arow0 > M - 1) arow0 = M - 1;
    if (arow1 > M - 1) arow1 = M - 1;
    const bf16* gA0 = A + (size_t)arow0 * Kfull + colbase + sc8;
    const bf16* gA1 = A + (size_t)arow1 * Kfull + colbase + sc8;
    const bf16* gB0 = BT + (size_t)(bx * 128 + wave * 16 + sr) * Kfull + colbase + sc8;
    const bf16* gB1 = BT + (size_t)(bx * 128 + wave * 16 + sr + 64) * Kfull + colbase + sc8;
    short* lA0 = As + wave * 512;
    short* lA1 = As + wave * 512 + 2048;
    short* lB0 = Bs + wave * 512;
    short* lB1 = Bs + wave * 512 + 2048;

    int fr = lane & 15;
    int fk = (lane >> 4) << 3;
    const short* pAf = As + (wr * 64 + fr) * 32 + fk;
    const short* pBf = Bs + (wc * 64 + fr) * 32 + fk;

    for (int kt = 0; kt < Kc; kt += 32) {
        if constexpr (GATHER) {
            int abs0 = colbase + kt;
            int ch = (abs0 >= 768) + (abs0 >= 1536);
            int col = abs0 - ch * 768 + sc8;
            int n0 = (ch == 0) ? arow0 : (2 * arow0 + ch);
            int n1 = (ch == 0) ? arow1 : (2 * arow1 + ch);
            gload16(A + (size_t)n0 * HD + col, lA0);
            gload16(A + (size_t)n1 * HD + col, lA1);
        } else {
            gload16(gA0 + kt, lA0);
            gload16(gA1 + kt, lA1);
        }
        gload16(gB0 + kt, lB0);
        gload16(gB1 + kt, lB1);
        __syncthreads();

        bf16x8 a[4], b[4];
#pragma unroll
        for (int m = 0; m < 4; m++) a[m] = *(const bf16x8*)(pAf + m * 512);
#pragma unroll
        for (int n = 0; n < 4; n++) b[n] = *(const bf16x8*)(pBf + n * 512);
#pragma unroll
        for (int m = 0; m < 4; m++)
#pragma unroll
            for (int n = 0; n < 4; n++)
                acc[m][n] = __builtin_amdgcn_mfma_f32_16x16x32_bf16(
                    a[m], b[n], acc[m][n], 0, 0, 0);
        __syncthreads();
    }

    int rbase = by * 128 + wr * 64 + ((lane >> 4) << 2);
    int cbase = bx * 128 + wc * 64 + fr;
#pragma unroll
    for (int m = 0; m < 4; m++) {
#pragma unroll
        for (int r = 0; r < 4; r++) {
            int row = rbase + m * 16 + r;
            if (row >= M) continue;
#pragma unroll
            for (int n = 0; n < 4; n++) {
                int col = cbase + n * 16;
                float v = acc[m][n][r];
                if constexpr (EPI == 1) {
                    v = fmaxf(v + bias[col], 0.f);
                    Cb[(size_t)row * N + col] = f2b(v);
                } else if constexpr (EPI == 3) {
                    Cb[(size_t)row * N + col] = f2b(v);
                } else {
                    Cf[(size_t)row * N + col] = v;
                }
            }
        }
    }
}

// ---------------------------------------------------------------------------
// Pass-1 cell (R8 scalar form): bf16 S(m x 3840) -> bf16 h,c. (big levels)
// ---------------------------------------------------------------------------
__global__ __launch_bounds__(256) void cell1_k(
    const int* __restrict__ ids, const bf16* __restrict__ S,
    const float* __restrict__ Wiou, const float* __restrict__ biou,
    const float* __restrict__ Wf, const float* __restrict__ bfv,
    bf16* __restrict__ h_all, bf16* __restrict__ c_all,
    int m, int offAbs)
{
    int idx = blockIdx.x * blockDim.x + threadIdx.x;
    if (idx >= m * HD) return;
    int i = idx / HD, j = idx - i * HD;
    int g = offAbs + i;
    int id = ids[g];
    const bf16* s = S + (size_t)i * 3840;
    const float* w = Wiou + (size_t)id * 2304;
    float iv = sigm(b2f(s[j]) + w[j] + biou[j]);
    float ov = sigm(b2f(s[HD + j]) + w[HD + j] + biou[HD + j]);
    float gv = tanhf(b2f(s[2 * HD + j]) + w[2 * HD + j] + biou[2 * HD + j]);
    float xf = Wf[(size_t)id * HD + j] + bfv[j];
    float f0 = sigm(b2f(s[3 * HD + j]) + xf);
    float f1 = sigm(b2f(s[4 * HD + j]) + xf);
    float c = iv * gv
            + f0 * b2f(c_all[(size_t)(2 * g + 1) * HD + j])
            + f1 * b2f(c_all[(size_t)(2 * g + 2) * HD + j]);
    h_all[(size_t)g * HD + j] = f2b(ov * tanhf(c));
    c_all[(size_t)g * HD + j] = f2b(c);
}

// ---------------------------------------------------------------------------
// Pass-1 cell, split-K variant: sums KS fp32 partials Sf[z][m][3840].
// ---------------------------------------------------------------------------
__global__ __launch_bounds__(256) void cell1s_k(
    const int* __restrict__ ids, const float* __restrict__ Sf,
    const float* __restrict__ Wiou, const float* __restrict__ biou,
    const float* __restrict__ Wf, const float* __restrict__ bfv,
    bf16* __restrict__ h_all, bf16* __restrict__ c_all,
    int m, int offAbs, int KS)
{
    int idx = blockIdx.x * blockDim.x + threadIdx.x;
    if (idx >= m * HD) return;
    int i = idx / HD, j = idx - i * HD;
    int g = offAbs + i;
    int id = ids[g];
    const float* s = Sf + (size_t)i * 3840;
    size_t zs = (size_t)m * 3840;
    float si = 0.f, so = 0.f, su = 0.f, p0 = 0.f, p1 = 0.f;
    for (int z = 0; z < KS; ++z) {
        const float* sz = s + z * zs;
        si += sz[j];
        so += sz[HD + j];
        su += sz[2 * HD + j];
        p0 += sz[3 * HD + j];
        p1 += sz[4 * HD + j];
    }
    const float* w = Wiou + (size_t)id * 2304;
    float iv = sigm(si + w[j] + biou[j]);
    float ov = sigm(so + w[HD + j] + biou[HD + j]);
    float gv = tanhf(su + w[2 * HD + j] + biou[2 * HD + j]);
    float xf = Wf[(size_t)id * HD + j] + bfv[j];
    float f0 = sigm(p0 + xf);
    float f1 = sigm(p1 + xf);
    float c = iv * gv
            + f0 * b2f(c_all[(size_t)(2 * g + 1) * HD + j])
            + f1 * b2f(c_all[(size_t)(2 * g + 2) * HD + j]);
    h_all[(size_t)g * HD + j] = f2b(ov * tanhf(c));
    c_all[(size_t)g * HD + j] = f2b(c);
}

// ---------------------------------------------------------------------------
// Pass-2 cell (R8 scalar form): bf16 S(m x 4608) -> bf16 h3.
// ---------------------------------------------------------------------------
__global__ __launch_bounds__(256) void cell2_k(
    const int* __restrict__ ids, const bf16* __restrict__ S,
    const float* __restrict__ Wiou, const float* __restrict__ biou,
    const float* __restrict__ Wf, const float* __restrict__ bfv,
    const bf16* __restrict__ c_all, bf16* __restrict__ h3_all,
    int m, int g0)
{
    int idx = blockIdx.x * blockDim.x + threadIdx.x;
    if (idx >= m * HD) return;
    int i = idx / HD, j = idx - i * HD;
    int g = g0 + i;
    int id = ids[g];
    const bf16* s = S + (size_t)i * 4608;
    const float* w = Wiou + (size_t)id * 2304;
    float iv = sigm(b2f(s[j]) + w[j] + biou[j]);
    float ov = sigm(b2f(s[HD + j]) + w[HD + j] + biou[HD + j]);
    float gv = tanhf(b2f(s[2 * HD + j]) + w[2 * HD + j] + biou[2 * HD + j]);
    float xf = Wf[(size_t)id * HD + j] + bfv[j];
    float f0 = sigm(b2f(s[3 * HD + j]) + xf);
    float f1 = sigm(b2f(s[4 * HD + j]) + xf);
    float f2 = sigm(b2f(s[5 * HD + j]) + xf);
    float c = iv * gv
            + f0 * b2f(c_all[(size_t)g * HD + j])
            + f1 * b2f(c_all[(size_t)(2 * g + 1) * HD + j])
            + f2 * b2f(c_all[(size_t)(2 * g + 2) * HD + j]);
    h3_all[(size_t)g * HD + j] = f2b(ov * tanhf(c));
}

// ---------------------------------------------------------------------------
// Head softmaxes from logits L[g][128]; bc holds fused biases. fp32 out.
// ---------------------------------------------------------------------------
__global__ __launch_bounds__(256) void hsm_k(
    const float* __restrict__ L, const int* __restrict__ mask,
    const float* __restrict__ bc, float* __restrict__ out)
{
    int g = blockIdx.x * 4 + (threadIdx.x >> 6);
    if (g >= N_NODES) return;
    int t = threadIdx.x & 63;
    const float* lr = L + (size_t)g * 128;

    bool on = mask[(size_t)g * 64 + t] > 0;
    float x = (lr[4 + t] + bc[4 + t]) * (1.0f / TEMP);
    float mx = on ? x : -INFINITY;
#pragma unroll
    for (int o = 32; o; o >>= 1) mx = fmaxf(mx, __shfl_xor(mx, o));
    float e = on ? __expf(x - mx) : 0.0f;
    float s = e;
#pragma unroll
    for (int o = 32; o; o >>= 1) s += __shfl_xor(s, o);
    float r = (s > 0.f) ? e / s : (1.0f / 64.0f);
    out[(size_t)g * 68 + 4 + t] = r;

    if (t == 0) {
        float a = (lr[0] + bc[0]) * (1.0f / TEMP);
        float b = (lr[1] + bc[1]) * (1.0f / TEMP);
        float m2 = fmaxf(a, b);
        float e0 = __expf(a - m2), e1 = __expf(b - m2);
        out[(size_t)g * 68 + 0] = e0 / (e0 + e1);
        out[(size_t)g * 68 + 1] = e1 / (e0 + e1);
    } else if (t == 1) {
        float a = (lr[2] + bc[2]) * (1.0f / TEMP);
        float b = (lr[3] + bc[3]) * (1.0f / TEMP);
        float m2 = fmaxf(a, b);
        float e0 = __expf(a - m2), e1 = __expf(b - m2);
        out[(size_t)g * 68 + 2] = e0 / (e0 + e1);
        out[(size_t)g * 68 + 3] = e1 / (e0 + e1);
    }
}

// ---------------------------------------------------------------------------
extern "C" void kernel_launch(void* const* d_in, const int* in_sizes, int n_in,
                              void* d_out, int out_size, void* d_ws, size_t ws_size,
                              hipStream_t stream)
{
    const int*   ids     = (const int*)d_in[0];
    const int*   mask    = (const int*)d_in[1];
    const float* Wb_iou  = (const float*)d_in[2];
    const float* Ub_iou  = (const float*)d_in[3];
    const float* bb_iou  = (const float*)d_in[4];
    const float* Wb_f    = (const float*)d_in[5];
    const float* Ub_f    = (const float*)d_in[6];
    const float* bb_f    = (const float*)d_in[7];
    const float* Wt_iou  = (const float*)d_in[8];
    const float* Ut_iou  = (const float*)d_in[9];
    const float* bt_iou  = (const float*)d_in[10];
    const float* Wt_f    = (const float*)d_in[11];
    const float* Ut_f    = (const float*)d_in[12];
    const float* bt_f    = (const float*)d_in[13];
    const float* ffn_W1  = (const float*)d_in[14];
    const float* ffn_b1  = (const float*)d_in[15];
    const float* ffn_W2  = (const float*)d_in[16];
    const float* ffn_b2  = (const float*)d_in[17];
    const float* hl_W    = (const float*)d_in[18];
    const float* hl_b    = (const float*)d_in[19];
    const float* int_W   = (const float*)d_in[20];
    const float* int_b   = (const float*)d_in[21];
    const float* act_W   = (const float*)d_in[22];
    const float* act_b   = (const float*)d_in[23];

    // ---- workspace layout ----
    char* p = (char*)d_ws;
    bf16* h_all  = (bf16*)p; p += (size_t)NHF * 2;
    bf16* c_all  = (bf16*)p; p += (size_t)NHF * 2;
    bf16* h3_all = (bf16*)p; p += (size_t)NHF * 2;
    bf16* BT1 = (bf16*)p; p += (size_t)T1SZ * 2;
    bf16* BT2 = (bf16*)p; p += (size_t)T2SZ * 2;
    bf16* W1T = (bf16*)p; p += (size_t)WSZ * 2;
    bf16* WcT = (bf16*)p; p += (size_t)128 * 768 * 2;
    bf16* WhT = (bf16*)p; p += (size_t)HSZ2 * 2;
    bf16* W2b = (bf16*)p; p += (size_t)WSZ * 2;
    float* bc = (float*)p; p += 512;
    bf16* Sb  = (bf16*)p;              // bf16 S: up to 8191 x 4608 = 75.5 MB
    float* Sf = (float*)Sb;            // fp32 split-K partials (tail levels)
    bf16* t1  = c_all;                 // FFN hidden aliases dead c
    float* Lg = (float*)h3_all;        // head logits alias h3 (dead after FFN1)

    // ---- weight conversions (coalesced) ----
    tconv_k<<<16704, 256, 0, stream>>>(
        Ub_iou, Ub_f, Ut_iou, Ut_f, ffn_W1, BT1, BT2, W1T);
    misc_k<<<(HSZ2 + WSZ + 255) / 256, 256, 0, stream>>>(
        hl_W, int_W, act_W, ffn_W2, WhT, W2b);
    bck_k<<<1, 128, 0, stream>>>(
        ffn_b2, hl_W, hl_b, int_W, int_b, act_W, act_b, bc);
    // WcT[n][k] = sum_j WhT[n][j] * W2[k][j]  (MFMA fold of FFN2 into heads)
    mm_k<3, 0><<<dim3(6, 1), 256, 0, stream>>>(
        WhT, W2b, nullptr, WcT, nullptr, 128, 768, 768, 768);

    leaf_k<<<(8192 * HD + 255) / 256, 256, 0, stream>>>(
        ids, Wb_iou, bb_iou, Wt_iou, bt_iou, h_all, c_all, h3_all);

    // ---- pass 1: big levels split mm+cell; small levels split-K (KS=6) ----
    for (int d = 12; d >= 0; --d) {
        int n = 1 << d;
        int childoff = 2 * n - 1;
        if (n >= 512) {
            mm_k<3, 0><<<dim3(30, n / 128), 256, 0, stream>>>(
                h_all + (size_t)childoff * HD, BT1, nullptr, Sb, nullptr,
                n, 3840, 1536, 1536);
            cell1_k<<<(n * HD + 255) / 256, 256, 0, stream>>>(
                ids, Sb, Wb_iou, bb_iou, Wb_f, bb_f, h_all, c_all, n, n - 1);
        } else {
            // split-K: 6 chunks of Kc=256, fp32 partials, summed in cell1s
            mm_k<0, 0><<<dim3(30, (n + 127) / 128, 6), 256, 0, stream>>>(
                h_all + (size_t)childoff * HD, BT1, Sf, nullptr, nullptr,
                n, 3840, 256, 1536);
            cell1s_k<<<(n * HD + 255) / 256, 256, 0, stream>>>(
                ids, Sf, Wb_iou, bb_iou, Wb_f, bb_f, h_all, c_all, n, n - 1, 6);
        }
    }

    // ---- pass 2: single chunk, gather fused into GEMM ----
    mm_k<3, 1><<<dim3(36, 64), 256, 0, stream>>>(
        h_all, BT2, nullptr, Sb, nullptr, NLEAF_OFF, 4608, 2304, 2304);
    cell2_k<<<(NLEAF_OFF * HD + 255) / 256, 256, 0, stream>>>(
        ids, Sb, Wt_iou, bt_iou, Wt_f, bt_f, c_all, h3_all, NLEAF_OFF, 0);

    // ---- FFN1 (relu epilogue) ----
    mm_k<1, 0><<<dim3(6, 128), 256, 0, stream>>>(
        h3_all, W1T, nullptr, t1, ffn_b1, N_NODES, 768, 768, 768);

    // ---- heads: folded logits GEMM (t1 @ WcT, FFN2 absorbed) + softmax ----
    mm_k<0, 0><<<dim3(1, 128), 256, 0, stream>>>(
        t1, WcT, Lg, nullptr, nullptr, N_NODES, 128, 768, 768);
    hsm_k<<<(N_NODES + 3) / 4, 256, 0, stream>>>(
        Lg, mask, bc, (float*)d_out);
}